// Round 5
// baseline (726.362 us; speedup 1.0000x reference)
//
#include <hip/hip_runtime.h>
#include <math.h>

#define N_NODES 100000
#define N_EDGES 1280000
#define DIM 64
#define N_GRAPHS 1000
#define BN_EPS 1e-5f
#define SCAN_BLOCKS 392   // 392*256 = 100352 >= N_NODES

// ---- bf16 helpers (top 16 bits of fp32, RTN pack) ----
__device__ __forceinline__ unsigned int bf16_rtn2(float a, float b) {
    unsigned int ua = __float_as_uint(a);
    unsigned int ub = __float_as_uint(b);
    ua = (ua + 0x7FFFu + ((ua >> 16) & 1u)) >> 16;
    ub = (ub + 0x7FFFu + ((ub >> 16) & 1u)) >> 16;
    return ua | (ub << 16);
}
__device__ __forceinline__ float bflo(unsigned int u) { return __uint_as_float(u << 16); }
__device__ __forceinline__ float bfhi(unsigned int u) { return __uint_as_float(u & 0xFFFF0000u); }

// ---------------- degree + per-graph count (merged) ----------------
__global__ void k_degcnt(const int* __restrict__ ei, const int* __restrict__ batch,
                         int* __restrict__ degc, float* __restrict__ cnt) {
    int idx = blockIdx.x * blockDim.x + threadIdx.x;
    if (idx < N_EDGES) atomicAdd(&degc[ei[N_EDGES + idx]], 1);
    if (idx < N_NODES) atomicAdd(&cnt[batch[idx]], 1.f);
}

// ---------------- 3-step exclusive scan of deg -> rowstart ----------------
__global__ void k_scan1(const int* __restrict__ deg, int* __restrict__ iscan,
                        int* __restrict__ bsum) {
    __shared__ int ls[256];
    int i = blockIdx.x * 256 + threadIdx.x;
    int v = (i < N_NODES) ? deg[i] : 0;
    ls[threadIdx.x] = v;
    __syncthreads();
    for (int off = 1; off < 256; off <<= 1) {
        int t = (threadIdx.x >= off) ? ls[threadIdx.x - off] : 0;
        __syncthreads();
        ls[threadIdx.x] += t;
        __syncthreads();
    }
    if (i < N_NODES) iscan[i] = ls[threadIdx.x];
    if (threadIdx.x == 255) bsum[blockIdx.x] = ls[255];
}

__global__ void k_scan2(const int* __restrict__ bsum, int* __restrict__ boff) {
    __shared__ int ls[512];
    int t = threadIdx.x;
    int v0 = (t < SCAN_BLOCKS) ? bsum[t] : 0;
    ls[t] = v0;
    __syncthreads();
    for (int off = 1; off < 512; off <<= 1) {
        int v = (t >= off) ? ls[t - off] : 0;
        __syncthreads();
        ls[t] += v;
        __syncthreads();
    }
    if (t < SCAN_BLOCKS) boff[t] = ls[t] - v0;  // exclusive
}

// rowstart + cursor + dinv in one pass
__global__ void k_scan3(const int* __restrict__ deg, const int* __restrict__ iscan,
                        const int* __restrict__ boff, int* __restrict__ rowstart,
                        int* __restrict__ cursor, float* __restrict__ dinv) {
    int i = blockIdx.x * 256 + threadIdx.x;
    if (i < N_NODES) {
        int rs = boff[blockIdx.x] + iscan[i] - deg[i];
        rowstart[i] = rs;
        cursor[i] = rs;
        dinv[i] = 1.0f / sqrtf((float)(deg[i] + 1));
    }
    if (i == 0) rowstart[N_NODES] = N_EDGES;
}

// fill CSR (by destination): csr_ew[pos] = {src, bits(dinv[src]*dinv[dst])}
__global__ void k_fill(const int* __restrict__ ei, const float* __restrict__ dinv,
                       int* __restrict__ cursor, int2* __restrict__ csr_ew) {
    int e = blockIdx.x * blockDim.x + threadIdx.x;
    if (e < N_EDGES) {
        int r = ei[e], c = ei[N_EDGES + e];
        int pos = atomicAdd(&cursor[c], 1);
        csr_ew[pos] = make_int2(r, (int)__float_as_uint(dinv[r] * dinv[c]));
    }
}

// ---------------- input BN statistics ----------------
__global__ void k_stats_x(const float* __restrict__ X,
                          float* __restrict__ gsum, float* __restrict__ gsumsq) {
    int j = threadIdx.x & 63, rg = threadIdx.x >> 6;
    float s = 0.f, s2 = 0.f;
    for (int i = blockIdx.x * 4 + rg; i < N_NODES; i += gridDim.x * 4) {
        float v = X[i * DIM + j];
        s += v; s2 += v * v;
    }
    __shared__ float ls[256], ls2[256];
    ls[threadIdx.x] = s; ls2[threadIdx.x] = s2;
    __syncthreads();
    if (threadIdx.x < 64) {
        s  = ls[j]  + ls[64 + j]  + ls[128 + j]  + ls[192 + j];
        s2 = ls2[j] + ls2[64 + j] + ls2[128 + j] + ls2[192 + j];
        atomicAdd(&gsum[j], s);
        atomicAdd(&gsumsq[j], s2);
    }
}

// scale/shift + folded cshift in one single-block kernel
__global__ void k_bnfold(const float* __restrict__ gsum, const float* __restrict__ gsumsq,
                         const float* __restrict__ g, const float* __restrict__ b,
                         const float* __restrict__ W,
                         float* __restrict__ scale, float* __restrict__ cshift) {
    int j = threadIdx.x;
    float mean = gsum[j] * (1.0f / N_NODES);
    float var  = gsumsq[j] * (1.0f / N_NODES) - mean * mean;
    float inv  = 1.0f / sqrtf(var + BN_EPS);
    float sc   = g[j] * inv;
    scale[j] = sc;
    __shared__ float shl[64];
    shl[j] = b[j] - mean * sc;
    __syncthreads();
    float s = 0.f;
    for (int k = 0; k < DIM; k++) s += shl[k] * W[k * DIM + j];
    cshift[j] = s;
}

// plain BN coefficients (for the post-pool BN2)
__global__ void k_bnfinal(const float* __restrict__ gsum, const float* __restrict__ gsumsq,
                          const float* __restrict__ g, const float* __restrict__ b,
                          float* __restrict__ scale, float* __restrict__ shift) {
    int j = threadIdx.x;
    float mean = gsum[j] * (1.0f / N_NODES);
    float var  = gsumsq[j] * (1.0f / N_NODES) - mean * mean;
    float inv  = 1.0f / sqrtf(var + BN_EPS);
    float sc   = g[j] * inv;
    scale[j] = sc;
    shift[j] = b[j] - mean * sc;
}

// ---------------- GEMM: T(bf16) = (X*scale) @ W + cshift ----------------
__global__ __launch_bounds__(256) void k_gemm(const float* __restrict__ X,
                                              const float* __restrict__ W,
                                              const float* __restrict__ scale,
                                              const float* __restrict__ cshift,
                                              unsigned short* __restrict__ T) {
    __shared__ float Wl[64 * 64];
    __shared__ float Al[64 * 65];
    for (int t = threadIdx.x; t < 4096; t += 256) {
        int k = t >> 6;
        Wl[t] = W[t] * scale[k];
    }
    int row0 = blockIdx.x * 64;
    for (int t = threadIdx.x; t < 4096; t += 256) {
        int r = t >> 6, k = t & 63;
        int i = row0 + r;
        Al[r * 65 + k] = (i < N_NODES) ? X[i * DIM + k] : 0.f;
    }
    __syncthreads();

    int r = threadIdx.x & 63;
    int q = threadIdx.x >> 6;
    float acc[16];
    #pragma unroll
    for (int jj = 0; jj < 16; jj++) acc[jj] = cshift[q * 16 + jj];

    #pragma unroll 4
    for (int k = 0; k < 64; k++) {
        float a = Al[r * 65 + k];
        const float4* wv = (const float4*)&Wl[k * 64 + q * 16];
        float4 w0 = wv[0], w1 = wv[1], w2 = wv[2], w3 = wv[3];
        acc[0]  += a * w0.x; acc[1]  += a * w0.y; acc[2]  += a * w0.z; acc[3]  += a * w0.w;
        acc[4]  += a * w1.x; acc[5]  += a * w1.y; acc[6]  += a * w1.z; acc[7]  += a * w1.w;
        acc[8]  += a * w2.x; acc[9]  += a * w2.y; acc[10] += a * w2.z; acc[11] += a * w2.w;
        acc[12] += a * w3.x; acc[13] += a * w3.y; acc[14] += a * w3.z; acc[15] += a * w3.w;
    }
    int i = row0 + r;
    if (i < N_NODES) {
        unsigned int pk[8];
        #pragma unroll
        for (int jj = 0; jj < 8; jj++) pk[jj] = bf16_rtn2(acc[2 * jj], acc[2 * jj + 1]);
        uint4* outv = (uint4*)&T[(size_t)i * DIM + q * 16];
        outv[0] = make_uint4(pk[0], pk[1], pk[2], pk[3]);
        outv[1] = make_uint4(pk[4], pk[5], pk[6], pk[7]);
    }
}

// ---------------- gather conv layer 1 ----------------
// wave = 4 edge-slots x 16 lanes; lane = uint2 (4 bf16 features).
// 2-deep software pipeline: 8 row-gathers in flight; csr record loads
// prefetched one iteration ahead (off the critical chain).
__global__ __launch_bounds__(256) void k_gather1(const unsigned short* __restrict__ T,
                                                 const float* __restrict__ dinv,
                                                 const int* __restrict__ rowstart,
                                                 const int2* __restrict__ csr_ew,
                                                 const float* __restrict__ bias,
                                                 float* __restrict__ H,
                                                 float* __restrict__ gsum,
                                                 float* __restrict__ gsumsq) {
    int lane = threadIdx.x & 63;
    int sub  = lane >> 4;        // edge slot 0..3
    int fq   = lane & 15;        // uint2 feature group (features 4fq..4fq+3)
    int wv   = threadIdx.x >> 6;
    int wid = blockIdx.x * 4 + wv;
    int nw = gridDim.x * 4;
    int per = (N_NODES + nw - 1) / nw;
    int i0 = wid * per;
    int i1 = min(i0 + per, N_NODES);
    const uint2* T2 = (const uint2*)T;   // row = 16 uint2 = 128 B
    float4 bb = ((const float4*)bias)[fq];
    float4 s4  = make_float4(0.f, 0.f, 0.f, 0.f);
    float4 s24 = make_float4(0.f, 0.f, 0.f, 0.f);
    int e0 = (i0 < i1) ? rowstart[i0] : 0;
    for (int i = i0; i < i1; i++) {
        int e1 = rowstart[i + 1];
        // issue self-loop row + dinv early (overlaps edge loop)
        float di = dinv[i];
        uint2 ts = T2[(size_t)i * 16 + fq];
        float a0 = 0.f, a1 = 0.f, a2 = 0.f, a3 = 0.f;
        int ecnt = e1 - e0;
        if (ecnt > 0) {
            int base = e0 + sub;
            int nit = (ecnt + 3) >> 2;      // max trips over the 4 slots
            // prologue: records for trips 0,1
            int  ia = base,     ib = base + 4;
            bool pa = ia < e1,  pb = ib < e1;
            int2 ra = csr_ew[pa ? ia : e0];
            int2 rb = csr_ew[pb ? ib : e0];
            for (int t = 0; t < nit; t += 2) {
                // gathers for both trips (independent -> both in flight)
                uint2 g0 = T2[(size_t)ra.x * 16 + fq];
                uint2 g1 = T2[(size_t)rb.x * 16 + fq];
                float w0 = pa ? __uint_as_float((unsigned int)ra.y) : 0.f;
                float w1 = pb ? __uint_as_float((unsigned int)rb.y) : 0.f;
                // prefetch next pair of records
                int  in0 = base + (t + 2) * 4, in1 = base + (t + 3) * 4;
                pa = in0 < e1; pb = in1 < e1;
                ra = csr_ew[pa ? in0 : e0];
                rb = csr_ew[pb ? in1 : e0];
                a0 += bflo(g0.x) * w0; a1 += bfhi(g0.x) * w0;
                a2 += bflo(g0.y) * w0; a3 += bfhi(g0.y) * w0;
                a0 += bflo(g1.x) * w1; a1 += bfhi(g1.x) * w1;
                a2 += bflo(g1.y) * w1; a3 += bfhi(g1.y) * w1;
            }
        }
        // reduce the 4 edge slots (2 butterfly levels)
        a0 += __shfl_xor(a0, 16, 64); a1 += __shfl_xor(a1, 16, 64);
        a2 += __shfl_xor(a2, 16, 64); a3 += __shfl_xor(a3, 16, 64);
        a0 += __shfl_xor(a0, 32, 64); a1 += __shfl_xor(a1, 32, 64);
        a2 += __shfl_xor(a2, 32, 64); a3 += __shfl_xor(a3, 32, 64);
        // self-loop + bias + relu
        float sw = di * di;
        float h0 = fmaxf(a0 + bflo(ts.x) * sw + bb.x, 0.f);
        float h1 = fmaxf(a1 + bfhi(ts.x) * sw + bb.y, 0.f);
        float h2 = fmaxf(a2 + bflo(ts.y) * sw + bb.z, 0.f);
        float h3 = fmaxf(a3 + bfhi(ts.y) * sw + bb.w, 0.f);
        if (sub == 0) {
            ((float4*)H)[(size_t)i * 16 + fq] = make_float4(h0, h1, h2, h3);
            s4.x += h0; s4.y += h1; s4.z += h2; s4.w += h3;
            s24.x += h0 * h0; s24.y += h1 * h1; s24.z += h2 * h2; s24.w += h3 * h3;
        }
        e0 = e1;
    }
    __shared__ float ls[4 * 64], ls2[4 * 64];
    if (sub == 0) {
        ls[wv * 64 + 4 * fq + 0] = s4.x;  ls2[wv * 64 + 4 * fq + 0] = s24.x;
        ls[wv * 64 + 4 * fq + 1] = s4.y;  ls2[wv * 64 + 4 * fq + 1] = s24.y;
        ls[wv * 64 + 4 * fq + 2] = s4.z;  ls2[wv * 64 + 4 * fq + 2] = s24.z;
        ls[wv * 64 + 4 * fq + 3] = s4.w;  ls2[wv * 64 + 4 * fq + 3] = s24.w;
    }
    __syncthreads();
    if (threadIdx.x < 64) {
        int j = threadIdx.x;
        float a  = ls[j]  + ls[64 + j]  + ls[128 + j]  + ls[192 + j];
        float a2 = ls2[j] + ls2[64 + j] + ls2[128 + j] + ls2[192 + j];
        atomicAdd(&gsum[j], a);
        atomicAdd(&gsumsq[j], a2);
    }
}

// ---------------- gather conv layer 2: relu -> pool + BN stats (H2 never stored) ----------------
__global__ __launch_bounds__(256) void k_gather2(const unsigned short* __restrict__ T,
                                                 const float* __restrict__ dinv,
                                                 const int* __restrict__ rowstart,
                                                 const int2* __restrict__ csr_ew,
                                                 const float* __restrict__ bias,
                                                 const int* __restrict__ batch,
                                                 float* __restrict__ pool,
                                                 float* __restrict__ gsum,
                                                 float* __restrict__ gsumsq) {
    int lane = threadIdx.x & 63;
    int sub  = lane >> 4;
    int fq   = lane & 15;
    int wv   = threadIdx.x >> 6;
    int wid = blockIdx.x * 4 + wv;
    int nw = gridDim.x * 4;
    int per = (N_NODES + nw - 1) / nw;
    int i0 = wid * per;
    int i1 = min(i0 + per, N_NODES);
    const uint2* T2 = (const uint2*)T;
    float4 bb = ((const float4*)bias)[fq];
    float4 s4  = make_float4(0.f, 0.f, 0.f, 0.f);
    float4 s24 = make_float4(0.f, 0.f, 0.f, 0.f);
    float4 ps  = make_float4(0.f, 0.f, 0.f, 0.f);
    int cur_g = -1;
    int e0 = (i0 < i1) ? rowstart[i0] : 0;
    for (int i = i0; i < i1; i++) {
        int e1 = rowstart[i + 1];
        float di = dinv[i];
        uint2 ts = T2[(size_t)i * 16 + fq];
        float a0 = 0.f, a1 = 0.f, a2 = 0.f, a3 = 0.f;
        int ecnt = e1 - e0;
        if (ecnt > 0) {
            int base = e0 + sub;
            int nit = (ecnt + 3) >> 2;
            int  ia = base,     ib = base + 4;
            bool pa = ia < e1,  pb = ib < e1;
            int2 ra = csr_ew[pa ? ia : e0];
            int2 rb = csr_ew[pb ? ib : e0];
            for (int t = 0; t < nit; t += 2) {
                uint2 g0 = T2[(size_t)ra.x * 16 + fq];
                uint2 g1 = T2[(size_t)rb.x * 16 + fq];
                float w0 = pa ? __uint_as_float((unsigned int)ra.y) : 0.f;
                float w1 = pb ? __uint_as_float((unsigned int)rb.y) : 0.f;
                int  in0 = base + (t + 2) * 4, in1 = base + (t + 3) * 4;
                pa = in0 < e1; pb = in1 < e1;
                ra = csr_ew[pa ? in0 : e0];
                rb = csr_ew[pb ? in1 : e0];
                a0 += bflo(g0.x) * w0; a1 += bfhi(g0.x) * w0;
                a2 += bflo(g0.y) * w0; a3 += bfhi(g0.y) * w0;
                a0 += bflo(g1.x) * w1; a1 += bfhi(g1.x) * w1;
                a2 += bflo(g1.y) * w1; a3 += bfhi(g1.y) * w1;
            }
        }
        a0 += __shfl_xor(a0, 16, 64); a1 += __shfl_xor(a1, 16, 64);
        a2 += __shfl_xor(a2, 16, 64); a3 += __shfl_xor(a3, 16, 64);
        a0 += __shfl_xor(a0, 32, 64); a1 += __shfl_xor(a1, 32, 64);
        a2 += __shfl_xor(a2, 32, 64); a3 += __shfl_xor(a3, 32, 64);
        float sw = di * di;
        float h0 = fmaxf(a0 + bflo(ts.x) * sw + bb.x, 0.f);
        float h1 = fmaxf(a1 + bfhi(ts.x) * sw + bb.y, 0.f);
        float h2 = fmaxf(a2 + bflo(ts.y) * sw + bb.z, 0.f);
        float h3 = fmaxf(a3 + bfhi(ts.y) * sw + bb.w, 0.f);
        if (sub == 0) {
            s4.x += h0; s4.y += h1; s4.z += h2; s4.w += h3;
            s24.x += h0 * h0; s24.y += h1 * h1; s24.z += h2 * h2; s24.w += h3 * h3;
            int g = batch[i];                  // sorted -> rarely changes
            if (g != cur_g) {
                if (cur_g >= 0) {
                    atomicAdd(&pool[(size_t)cur_g * DIM + 4 * fq + 0], ps.x);
                    atomicAdd(&pool[(size_t)cur_g * DIM + 4 * fq + 1], ps.y);
                    atomicAdd(&pool[(size_t)cur_g * DIM + 4 * fq + 2], ps.z);
                    atomicAdd(&pool[(size_t)cur_g * DIM + 4 * fq + 3], ps.w);
                }
                ps = make_float4(0.f, 0.f, 0.f, 0.f);
                cur_g = g;
            }
            ps.x += h0; ps.y += h1; ps.z += h2; ps.w += h3;
        }
        e0 = e1;
    }
    if (sub == 0 && cur_g >= 0) {
        atomicAdd(&pool[(size_t)cur_g * DIM + 4 * fq + 0], ps.x);
        atomicAdd(&pool[(size_t)cur_g * DIM + 4 * fq + 1], ps.y);
        atomicAdd(&pool[(size_t)cur_g * DIM + 4 * fq + 2], ps.z);
        atomicAdd(&pool[(size_t)cur_g * DIM + 4 * fq + 3], ps.w);
    }
    __shared__ float ls[4 * 64], ls2[4 * 64];
    if (sub == 0) {
        ls[wv * 64 + 4 * fq + 0] = s4.x;  ls2[wv * 64 + 4 * fq + 0] = s24.x;
        ls[wv * 64 + 4 * fq + 1] = s4.y;  ls2[wv * 64 + 4 * fq + 1] = s24.y;
        ls[wv * 64 + 4 * fq + 2] = s4.z;  ls2[wv * 64 + 4 * fq + 2] = s24.z;
        ls[wv * 64 + 4 * fq + 3] = s4.w;  ls2[wv * 64 + 4 * fq + 3] = s24.w;
    }
    __syncthreads();
    if (threadIdx.x < 64) {
        int j = threadIdx.x;
        float a  = ls[j]  + ls[64 + j]  + ls[128 + j]  + ls[192 + j];
        float a2 = ls2[j] + ls2[64 + j] + ls2[128 + j] + ls2[192 + j];
        atomicAdd(&gsum[j], a);
        atomicAdd(&gsumsq[j], a2);
    }
}

// ---------------- final: out[g] = ((pool/cnt)*scale + shift) @ Wout + bout ----------------
__global__ void k_final(const float* __restrict__ pool, const float* __restrict__ cnt,
                        const float* __restrict__ scale, const float* __restrict__ shift,
                        const float* __restrict__ Wout, const float* __restrict__ bout,
                        float* __restrict__ out) {
    int g = blockIdx.x;
    int l = threadIdx.x;
    float c = fmaxf(cnt[g], 1.f);
    float p = (pool[g * DIM + l] / c) * scale[l] + shift[l];
    float a0 = p * Wout[l * 2 + 0];
    float a1 = p * Wout[l * 2 + 1];
    #pragma unroll
    for (int off = 32; off; off >>= 1) {
        a0 += __shfl_down(a0, off, 64);
        a1 += __shfl_down(a1, off, 64);
    }
    if (l == 0) {
        out[g * 2 + 0] = a0 + bout[0];
        out[g * 2 + 1] = a1 + bout[1];
    }
}

extern "C" void kernel_launch(void* const* d_in, const int* in_sizes, int n_in,
                              void* d_out, int out_size, void* d_ws, size_t ws_size,
                              hipStream_t stream) {
    (void)in_sizes; (void)n_in; (void)out_size; (void)ws_size;
    const float* x       = (const float*)d_in[0];
    const int*   ei      = (const int*)d_in[1];
    const int*   batch   = (const int*)d_in[2];
    const float* bn_in_g = (const float*)d_in[3];
    const float* bn_in_b = (const float*)d_in[4];
    const float* W1      = (const float*)d_in[5];
    const float* b1      = (const float*)d_in[6];
    const float* g1      = (const float*)d_in[7];
    const float* be1     = (const float*)d_in[8];
    const float* W2      = (const float*)d_in[9];
    const float* b2      = (const float*)d_in[10];
    const float* g2      = (const float*)d_in[11];
    const float* be2     = (const float*)d_in[12];
    const float* Wout    = (const float*)d_in[13];
    const float* bout    = (const float*)d_in[14];
    float* out = (float*)d_out;

    // workspace layout (~51 MB), 8B alignment maintained for csr_ew
    char* p = (char*)d_ws;
    float* H = (float*)p;             p += (size_t)N_NODES * DIM * 4;      // 25.6 MB fp32
    unsigned short* T = (unsigned short*)p; p += (size_t)N_NODES * DIM * 2; // 12.8 MB bf16
    float* dinv = (float*)p;          p += N_NODES * 4;
    int* degc = (int*)p;              p += N_NODES * 4;
    int* iscan = (int*)p;             p += N_NODES * 4;
    int* rowstart = (int*)p;          p += (N_NODES + 2) * 4;              // +2 keeps 8B align
    int* cursor = (int*)p;            p += N_NODES * 4;
    int2* csr_ew = (int2*)p;          p += (size_t)N_EDGES * 8;            // 10.24 MB
    int* bsum = (int*)p;              p += SCAN_BLOCKS * 4;
    int* boff = (int*)p;              p += SCAN_BLOCKS * 4;
    float* gsum = (float*)p;          p += DIM * 4;
    float* gsumsq = (float*)p;        p += DIM * 4;
    float* scale = (float*)p;         p += DIM * 4;
    float* shift = (float*)p;         p += DIM * 4;
    float* cshift = (float*)p;        p += DIM * 4;
    float* pool = (float*)p;          p += (size_t)N_GRAPHS * DIM * 4;
    float* cnt = (float*)p;           p += N_GRAPHS * 4;

    // ---- CSR build + norm coefficients ----
    hipMemsetAsync(degc, 0, N_NODES * sizeof(int), stream);
    hipMemsetAsync(pool, 0, (N_GRAPHS * DIM + N_GRAPHS) * sizeof(float), stream);
    k_degcnt<<<(N_EDGES + 255) / 256, 256, 0, stream>>>(ei, batch, degc, cnt);
    k_scan1<<<SCAN_BLOCKS, 256, 0, stream>>>(degc, iscan, bsum);
    k_scan2<<<1, 512, 0, stream>>>(bsum, boff);
    k_scan3<<<SCAN_BLOCKS, 256, 0, stream>>>(degc, iscan, boff, rowstart, cursor, dinv);
    k_fill<<<N_EDGES / 256, 256, 0, stream>>>(ei, dinv, cursor, csr_ew);

    // ---- input BN -> GEMM1 -> gather1 (fused bias+relu+stats) ----
    hipMemsetAsync(gsum, 0, 2 * DIM * sizeof(float), stream);
    k_stats_x<<<1024, 256, 0, stream>>>(x, gsum, gsumsq);
    k_bnfold<<<1, 64, 0, stream>>>(gsum, gsumsq, bn_in_g, bn_in_b, W1, scale, cshift);
    k_gemm<<<(N_NODES + 63) / 64, 256, 0, stream>>>(x, W1, scale, cshift, T);      // T1 (bf16)
    hipMemsetAsync(gsum, 0, 2 * DIM * sizeof(float), stream);
    k_gather1<<<4096, 256, 0, stream>>>(T, dinv, rowstart, csr_ew, b1, H, gsum, gsumsq); // H1 fp32

    // ---- BN1 -> GEMM2 -> gather2 (fused bias+relu+stats+pool) ----
    k_bnfold<<<1, 64, 0, stream>>>(gsum, gsumsq, g1, be1, W2, scale, cshift);
    k_gemm<<<(N_NODES + 63) / 64, 256, 0, stream>>>(H, W2, scale, cshift, T);      // T2 (bf16)
    hipMemsetAsync(gsum, 0, 2 * DIM * sizeof(float), stream);
    k_gather2<<<4096, 256, 0, stream>>>(T, dinv, rowstart, csr_ew, b2, batch, pool,
                                        gsum, gsumsq);

    // ---- BN2 (applied post-pool; BN affine, pool linear) -> linear ----
    k_bnfinal<<<1, 64, 0, stream>>>(gsum, gsumsq, g2, be2, scale, shift);
    k_final<<<N_GRAPHS, 64, 0, stream>>>(pool, cnt, scale, shift, Wout, bout, out);
}

// Round 6
// 558.509 us; speedup vs baseline: 1.3005x; 1.3005x over previous
//
#include <hip/hip_runtime.h>
#include <math.h>

#define N_NODES 100000
#define N_EDGES 1280000
#define DIM 64
#define N_GRAPHS 1000
#define BN_EPS 1e-5f
#define SCAN_BLOCKS 392   // 392*256 = 100352 >= N_NODES
#define WIN 128           // edges per wave window; N_EDGES/WIN = 10000 exactly
#define NWIN (N_EDGES / WIN)
#define GU 8              // edge unroll inside a window

// ---- bf16 helpers (top 16 bits of fp32, RTN pack) ----
__device__ __forceinline__ unsigned int bf16_rtn2(float a, float b) {
    unsigned int ua = __float_as_uint(a);
    unsigned int ub = __float_as_uint(b);
    ua = (ua + 0x7FFFu + ((ua >> 16) & 1u)) >> 16;
    ub = (ub + 0x7FFFu + ((ub >> 16) & 1u)) >> 16;
    return ua | (ub << 16);
}
__device__ __forceinline__ float bfup(unsigned short u) {
    return __uint_as_float(((unsigned int)u) << 16);
}

// ---------------- degree + per-graph count (merged) ----------------
__global__ void k_degcnt(const int* __restrict__ ei, const int* __restrict__ batch,
                         int* __restrict__ degc, float* __restrict__ cnt) {
    int idx = blockIdx.x * blockDim.x + threadIdx.x;
    if (idx < N_EDGES) atomicAdd(&degc[ei[N_EDGES + idx]], 1);
    if (idx < N_NODES) atomicAdd(&cnt[batch[idx]], 1.f);
}

// ---------------- 3-step exclusive scan of deg -> rowstart ----------------
__global__ void k_scan1(const int* __restrict__ deg, int* __restrict__ iscan,
                        int* __restrict__ bsum) {
    __shared__ int ls[256];
    int i = blockIdx.x * 256 + threadIdx.x;
    int v = (i < N_NODES) ? deg[i] : 0;
    ls[threadIdx.x] = v;
    __syncthreads();
    for (int off = 1; off < 256; off <<= 1) {
        int t = (threadIdx.x >= off) ? ls[threadIdx.x - off] : 0;
        __syncthreads();
        ls[threadIdx.x] += t;
        __syncthreads();
    }
    if (i < N_NODES) iscan[i] = ls[threadIdx.x];
    if (threadIdx.x == 255) bsum[blockIdx.x] = ls[255];
}

__global__ void k_scan2(const int* __restrict__ bsum, int* __restrict__ boff) {
    __shared__ int ls[512];
    int t = threadIdx.x;
    int v0 = (t < SCAN_BLOCKS) ? bsum[t] : 0;
    ls[t] = v0;
    __syncthreads();
    for (int off = 1; off < 512; off <<= 1) {
        int v = (t >= off) ? ls[t - off] : 0;
        __syncthreads();
        ls[t] += v;
        __syncthreads();
    }
    if (t < SCAN_BLOCKS) boff[t] = ls[t] - v0;  // exclusive
}

// rowstart + cursor + dinv + winnode in one pass
__global__ void k_scan3(const int* __restrict__ deg, const int* __restrict__ iscan,
                        const int* __restrict__ boff, int* __restrict__ rowstart,
                        int* __restrict__ cursor, float* __restrict__ dinv,
                        int* __restrict__ winnode) {
    int i = blockIdx.x * 256 + threadIdx.x;
    if (i < N_NODES) {
        int rs_end = boff[blockIdx.x] + iscan[i];
        int rs = rs_end - deg[i];
        rowstart[i] = rs;
        cursor[i] = rs;
        dinv[i] = 1.0f / sqrtf((float)(deg[i] + 1));
        // windows whose first edge lies in [rs, rs_end) are owned by node i
        for (int w = (rs + WIN - 1) / WIN; w * WIN < rs_end; ++w) winnode[w] = i;
    }
    if (i == 0) rowstart[N_NODES] = N_EDGES;
}

// fill CSR (by destination): csr_ew[pos] = {src, bits(dinv[src]*dinv[dst])}
// block 0 also zeros gsum/gsumsq for the following stats kernel
__global__ void k_fill(const int* __restrict__ ei, const float* __restrict__ dinv,
                       int* __restrict__ cursor, int2* __restrict__ csr_ew,
                       float* __restrict__ gsum) {
    if (blockIdx.x == 0 && threadIdx.x < 128) gsum[threadIdx.x] = 0.f;
    int e = blockIdx.x * blockDim.x + threadIdx.x;
    if (e < N_EDGES) {
        int r = ei[e], c = ei[N_EDGES + e];
        int pos = atomicAdd(&cursor[c], 1);
        csr_ew[pos] = make_int2(r, (int)__float_as_uint(dinv[r] * dinv[c]));
    }
}

// ---------------- input BN statistics ----------------
__global__ void k_stats_x(const float* __restrict__ X,
                          float* __restrict__ gsum, float* __restrict__ gsumsq) {
    int j = threadIdx.x & 63, rg = threadIdx.x >> 6;
    float s = 0.f, s2 = 0.f;
    for (int i = blockIdx.x * 4 + rg; i < N_NODES; i += gridDim.x * 4) {
        float v = X[i * DIM + j];
        s += v; s2 += v * v;
    }
    __shared__ float ls[256], ls2[256];
    ls[threadIdx.x] = s; ls2[threadIdx.x] = s2;
    __syncthreads();
    if (threadIdx.x < 64) {
        s  = ls[j]  + ls[64 + j]  + ls[128 + j]  + ls[192 + j];
        s2 = ls2[j] + ls2[64 + j] + ls2[128 + j] + ls2[192 + j];
        atomicAdd(&gsum[j], s);
        atomicAdd(&gsumsq[j], s2);
    }
}

// scale/shift + folded cshift in one single-block kernel
__global__ void k_bnfold(const float* __restrict__ gsum, const float* __restrict__ gsumsq,
                         const float* __restrict__ g, const float* __restrict__ b,
                         const float* __restrict__ W,
                         float* __restrict__ scale, float* __restrict__ cshift) {
    int j = threadIdx.x;
    float mean = gsum[j] * (1.0f / N_NODES);
    float var  = gsumsq[j] * (1.0f / N_NODES) - mean * mean;
    float inv  = 1.0f / sqrtf(var + BN_EPS);
    float sc   = g[j] * inv;
    scale[j] = sc;
    __shared__ float shl[64];
    shl[j] = b[j] - mean * sc;
    __syncthreads();
    float s = 0.f;
    for (int k = 0; k < DIM; k++) s += shl[k] * W[k * DIM + j];
    cshift[j] = s;
}

// plain BN coefficients (for the post-pool BN2)
__global__ void k_bnfinal(const float* __restrict__ gsum, const float* __restrict__ gsumsq,
                          const float* __restrict__ g, const float* __restrict__ b,
                          float* __restrict__ scale, float* __restrict__ shift) {
    int j = threadIdx.x;
    float mean = gsum[j] * (1.0f / N_NODES);
    float var  = gsumsq[j] * (1.0f / N_NODES) - mean * mean;
    float inv  = 1.0f / sqrtf(var + BN_EPS);
    float sc   = g[j] * inv;
    scale[j] = sc;
    shift[j] = b[j] - mean * sc;
}

// ---------------- GEMM: T(bf16) = (X*scale) @ W + cshift; also zero-inits C ----------------
__global__ __launch_bounds__(256) void k_gemm(const float* __restrict__ X,
                                              const float* __restrict__ W,
                                              const float* __restrict__ scale,
                                              const float* __restrict__ cshift,
                                              unsigned short* __restrict__ T,
                                              float* __restrict__ czero) {
    // strided zero of C (for the following gather's plain/atomic stores)
    float4 z4 = make_float4(0.f, 0.f, 0.f, 0.f);
    for (int t = blockIdx.x * 256 + threadIdx.x; t < N_NODES * (DIM / 4);
         t += gridDim.x * 256)
        ((float4*)czero)[t] = z4;

    __shared__ float Wl[64 * 64];
    __shared__ float Al[64 * 65];
    for (int t = threadIdx.x; t < 4096; t += 256) {
        int k = t >> 6;
        Wl[t] = W[t] * scale[k];
    }
    int row0 = blockIdx.x * 64;
    for (int t = threadIdx.x; t < 4096; t += 256) {
        int r = t >> 6, k = t & 63;
        int i = row0 + r;
        Al[r * 65 + k] = (i < N_NODES) ? X[i * DIM + k] : 0.f;
    }
    __syncthreads();

    int r = threadIdx.x & 63;
    int q = threadIdx.x >> 6;
    float acc[16];
    #pragma unroll
    for (int jj = 0; jj < 16; jj++) acc[jj] = cshift[q * 16 + jj];

    #pragma unroll 4
    for (int k = 0; k < 64; k++) {
        float a = Al[r * 65 + k];
        const float4* wv = (const float4*)&Wl[k * 64 + q * 16];
        float4 w0 = wv[0], w1 = wv[1], w2 = wv[2], w3 = wv[3];
        acc[0]  += a * w0.x; acc[1]  += a * w0.y; acc[2]  += a * w0.z; acc[3]  += a * w0.w;
        acc[4]  += a * w1.x; acc[5]  += a * w1.y; acc[6]  += a * w1.z; acc[7]  += a * w1.w;
        acc[8]  += a * w2.x; acc[9]  += a * w2.y; acc[10] += a * w2.z; acc[11] += a * w2.w;
        acc[12] += a * w3.x; acc[13] += a * w3.y; acc[14] += a * w3.z; acc[15] += a * w3.w;
    }
    int i = row0 + r;
    if (i < N_NODES) {
        unsigned int pk[8];
        #pragma unroll
        for (int jj = 0; jj < 8; jj++) pk[jj] = bf16_rtn2(acc[2 * jj], acc[2 * jj + 1]);
        uint4* outv = (uint4*)&T[(size_t)i * DIM + q * 16];
        outv[0] = make_uint4(pk[0], pk[1], pk[2], pk[3]);
        outv[1] = make_uint4(pk[4], pk[5], pk[6], pk[7]);
    }
}

// ---------------- edge-parallel gather: C[dst] += T[src]*w over a 128-edge window ----------
// wave = one window of WIN consecutive CSR edges; lane = feature.
// All row loads are fully coalesced (128 B, zero address divergence); 8 in flight.
// Node flushes: plain store if the node's edge range is inside the window,
// atomicAdd for the <=2 straddling nodes (C is pre-zeroed by k_gemm).
__global__ __launch_bounds__(256) void k_gather_ep(const unsigned short* __restrict__ T,
                                                   const int* __restrict__ rowstart,
                                                   const int* __restrict__ winnode,
                                                   const int2* __restrict__ csr_ew,
                                                   float* __restrict__ C,
                                                   float* __restrict__ gsum) {
    // block 0 zeros gsum/gsumsq for the following post kernel
    if (blockIdx.x == 0 && threadIdx.x < 128) gsum[threadIdx.x] = 0.f;
    int lane = threadIdx.x & 63;
    int w = blockIdx.x * 4 + (threadIdx.x >> 6);
    if (w >= NWIN) return;
    int e = w * WIN;
    const int eend = e + WIN;
    int i  = __builtin_amdgcn_readfirstlane(winnode[w]);
    int re = __builtin_amdgcn_readfirstlane(rowstart[i + 1]);
    bool part = __builtin_amdgcn_readfirstlane(rowstart[i]) < e;  // node started earlier
    float acc = 0.f;
    for (; e < eend; e += GU) {
        int   src[GU];
        float wt[GU];
        int eu = __builtin_amdgcn_readfirstlane(e);
        #pragma unroll
        for (int u = 0; u < GU; u++) {
            int2 ew = csr_ew[eu + u];            // wave-uniform -> scalar K$ loads
            src[u] = ew.x;
            wt[u]  = __uint_as_float((unsigned int)ew.y);
        }
        float tv[GU];
        #pragma unroll
        for (int u = 0; u < GU; u++)             // 8 independent coalesced 128B gathers
            tv[u] = bfup(T[(size_t)src[u] * DIM + lane]);
        #pragma unroll
        for (int u = 0; u < GU; u++) {
            while (e + u == re) {                // crossed into next node: flush i
                if (part) atomicAdd(&C[(size_t)i * DIM + lane], acc);
                else      C[(size_t)i * DIM + lane] = acc;
                acc = 0.f; part = false;
                ++i;
                re = __builtin_amdgcn_readfirstlane(rowstart[i + 1]);
            }
            acc += tv[u] * wt[u];
        }
    }
    // final flush: node complete at window end (re==eend) -> store, else partial -> atomic
    if (part || re > eend) atomicAdd(&C[(size_t)i * DIM + lane], acc);
    else                   C[(size_t)i * DIM + lane] = acc;
}

// ---------------- post layer 1: H = relu(C + self + bias), BN stats ----------------
__global__ __launch_bounds__(256) void k_post1(const float* __restrict__ C,
                                               const unsigned short* __restrict__ T,
                                               const float* __restrict__ dinv,
                                               const float* __restrict__ bias,
                                               float* __restrict__ H,
                                               float* __restrict__ gsum,
                                               float* __restrict__ gsumsq) {
    int lane = threadIdx.x & 63;
    int wv = threadIdx.x >> 6;
    int wid = blockIdx.x * 4 + wv;
    int nw = gridDim.x * 4;
    int per = (N_NODES + nw - 1) / nw;
    int i0 = wid * per, i1 = min(i0 + per, N_NODES);
    float bb = bias[lane];
    float s = 0.f, s2 = 0.f;
    for (int i = i0; i < i1; i++) {
        float di = dinv[i];
        float h = fmaxf(C[(size_t)i * DIM + lane]
                        + bfup(T[(size_t)i * DIM + lane]) * (di * di) + bb, 0.f);
        H[(size_t)i * DIM + lane] = h;
        s += h; s2 += h * h;
    }
    __shared__ float ls[256], ls2[256];
    ls[threadIdx.x] = s; ls2[threadIdx.x] = s2;
    __syncthreads();
    if (threadIdx.x < 64) {
        int j = threadIdx.x;
        float a  = ls[j]  + ls[64 + j]  + ls[128 + j]  + ls[192 + j];
        float a2 = ls2[j] + ls2[64 + j] + ls2[128 + j] + ls2[192 + j];
        atomicAdd(&gsum[j], a);
        atomicAdd(&gsumsq[j], a2);
    }
}

// ---------------- post layer 2: relu -> pool (run-flush) + BN stats ----------------
__global__ __launch_bounds__(256) void k_post2(const float* __restrict__ C,
                                               const unsigned short* __restrict__ T,
                                               const float* __restrict__ dinv,
                                               const float* __restrict__ bias,
                                               const int* __restrict__ batch,
                                               float* __restrict__ pool,
                                               float* __restrict__ gsum,
                                               float* __restrict__ gsumsq) {
    int lane = threadIdx.x & 63;
    int wv = threadIdx.x >> 6;
    int wid = blockIdx.x * 4 + wv;
    int nw = gridDim.x * 4;
    int per = (N_NODES + nw - 1) / nw;
    int i0 = wid * per, i1 = min(i0 + per, N_NODES);
    float bb = bias[lane];
    float s = 0.f, s2 = 0.f, ps = 0.f;
    int cur_g = -1;
    for (int i = i0; i < i1; i++) {
        float di = dinv[i];
        float h = fmaxf(C[(size_t)i * DIM + lane]
                        + bfup(T[(size_t)i * DIM + lane]) * (di * di) + bb, 0.f);
        s += h; s2 += h * h;
        int g = batch[i];                        // sorted -> rarely changes
        if (g != cur_g) {
            if (cur_g >= 0) atomicAdd(&pool[(size_t)cur_g * DIM + lane], ps);
            ps = 0.f; cur_g = g;
        }
        ps += h;
    }
    if (cur_g >= 0) atomicAdd(&pool[(size_t)cur_g * DIM + lane], ps);
    __shared__ float ls[256], ls2[256];
    ls[threadIdx.x] = s; ls2[threadIdx.x] = s2;
    __syncthreads();
    if (threadIdx.x < 64) {
        int j = threadIdx.x;
        float a  = ls[j]  + ls[64 + j]  + ls[128 + j]  + ls[192 + j];
        float a2 = ls2[j] + ls2[64 + j] + ls2[128 + j] + ls2[192 + j];
        atomicAdd(&gsum[j], a);
        atomicAdd(&gsumsq[j], a2);
    }
}

// ---------------- final: out[g] = ((pool/cnt)*scale + shift) @ Wout + bout ----------------
__global__ void k_final(const float* __restrict__ pool, const float* __restrict__ cnt,
                        const float* __restrict__ scale, const float* __restrict__ shift,
                        const float* __restrict__ Wout, const float* __restrict__ bout,
                        float* __restrict__ out) {
    int g = blockIdx.x;
    int l = threadIdx.x;
    float c = fmaxf(cnt[g], 1.f);
    float p = (pool[g * DIM + l] / c) * scale[l] + shift[l];
    float a0 = p * Wout[l * 2 + 0];
    float a1 = p * Wout[l * 2 + 1];
    #pragma unroll
    for (int off = 32; off; off >>= 1) {
        a0 += __shfl_down(a0, off, 64);
        a1 += __shfl_down(a1, off, 64);
    }
    if (l == 0) {
        out[g * 2 + 0] = a0 + bout[0];
        out[g * 2 + 1] = a1 + bout[1];
    }
}

extern "C" void kernel_launch(void* const* d_in, const int* in_sizes, int n_in,
                              void* d_out, int out_size, void* d_ws, size_t ws_size,
                              hipStream_t stream) {
    (void)in_sizes; (void)n_in; (void)out_size; (void)ws_size;
    const float* x       = (const float*)d_in[0];
    const int*   ei      = (const int*)d_in[1];
    const int*   batch   = (const int*)d_in[2];
    const float* bn_in_g = (const float*)d_in[3];
    const float* bn_in_b = (const float*)d_in[4];
    const float* W1      = (const float*)d_in[5];
    const float* b1      = (const float*)d_in[6];
    const float* g1      = (const float*)d_in[7];
    const float* be1     = (const float*)d_in[8];
    const float* W2      = (const float*)d_in[9];
    const float* b2      = (const float*)d_in[10];
    const float* g2      = (const float*)d_in[11];
    const float* be2     = (const float*)d_in[12];
    const float* Wout    = (const float*)d_in[13];
    const float* bout    = (const float*)d_in[14];
    float* out = (float*)d_out;

    // workspace layout (~77 MB), 8B alignment for csr_ew
    char* p = (char*)d_ws;
    float* H = (float*)p;                   p += (size_t)N_NODES * DIM * 4;  // 25.6 MB
    float* C = (float*)p;                   p += (size_t)N_NODES * DIM * 4;  // 25.6 MB
    unsigned short* T = (unsigned short*)p; p += (size_t)N_NODES * DIM * 2;  // 12.8 MB
    float* dinv = (float*)p;                p += N_NODES * 4;
    int* degc = (int*)p;                    p += N_NODES * 4;
    int* iscan = (int*)p;                   p += N_NODES * 4;
    int* rowstart = (int*)p;                p += (N_NODES + 2) * 4;          // 8B align kept
    int* cursor = (int*)p;                  p += N_NODES * 4;
    int2* csr_ew = (int2*)p;                p += (size_t)N_EDGES * 8;        // 10.24 MB
    int* winnode = (int*)p;                 p += NWIN * 4;                   // 40 KB
    int* bsum = (int*)p;                    p += SCAN_BLOCKS * 4;
    int* boff = (int*)p;                    p += SCAN_BLOCKS * 4;
    float* gsum = (float*)p;                p += DIM * 4;   // gsum[64] | gsumsq[64] contiguous
    float* gsumsq = (float*)p;              p += DIM * 4;
    float* scale = (float*)p;               p += DIM * 4;
    float* shift = (float*)p;               p += DIM * 4;
    float* cshift = (float*)p;              p += DIM * 4;
    float* pool = (float*)p;                p += (size_t)N_GRAPHS * DIM * 4;
    float* cnt = (float*)p;                 p += N_GRAPHS * 4;

    // ---- CSR build + norm coefficients ----
    hipMemsetAsync(degc, 0, N_NODES * sizeof(int), stream);
    hipMemsetAsync(pool, 0, (N_GRAPHS * DIM + N_GRAPHS) * sizeof(float), stream);
    k_degcnt<<<(N_EDGES + 255) / 256, 256, 0, stream>>>(ei, batch, degc, cnt);
    k_scan1<<<SCAN_BLOCKS, 256, 0, stream>>>(degc, iscan, bsum);
    k_scan2<<<1, 512, 0, stream>>>(bsum, boff);
    k_scan3<<<SCAN_BLOCKS, 256, 0, stream>>>(degc, iscan, boff, rowstart, cursor, dinv,
                                             winnode);
    k_fill<<<N_EDGES / 256, 256, 0, stream>>>(ei, dinv, cursor, csr_ew, gsum);

    // ---- input BN -> GEMM1 (+C zero) -> edge-parallel gather -> post1 ----
    k_stats_x<<<1024, 256, 0, stream>>>(x, gsum, gsumsq);
    k_bnfold<<<1, 64, 0, stream>>>(gsum, gsumsq, bn_in_g, bn_in_b, W1, scale, cshift);
    k_gemm<<<(N_NODES + 63) / 64, 256, 0, stream>>>(x, W1, scale, cshift, T, C);
    k_gather_ep<<<NWIN / 4, 256, 0, stream>>>(T, rowstart, winnode, csr_ew, C, gsum);
    k_post1<<<1024, 256, 0, stream>>>(C, T, dinv, b1, H, gsum, gsumsq);

    // ---- BN1 -> GEMM2 (+C zero) -> gather -> post2 (pool+stats) ----
    k_bnfold<<<1, 64, 0, stream>>>(gsum, gsumsq, g1, be1, W2, scale, cshift);
    k_gemm<<<(N_NODES + 63) / 64, 256, 0, stream>>>(H, W2, scale, cshift, T, C);
    k_gather_ep<<<NWIN / 4, 256, 0, stream>>>(T, rowstart, winnode, csr_ew, C, gsum);
    k_post2<<<1024, 256, 0, stream>>>(C, T, dinv, b2, batch, pool, gsum, gsumsq);

    // ---- BN2 (post-pool; BN affine, pool linear) -> linear ----
    k_bnfinal<<<1, 64, 0, stream>>>(gsum, gsumsq, g2, be2, scale, shift);
    k_final<<<N_GRAPHS, 64, 0, stream>>>(pool, cnt, scale, shift, Wout, bout, out);
}

// Round 7
// 506.989 us; speedup vs baseline: 1.4327x; 1.1016x over previous
//
#include <hip/hip_runtime.h>
#include <math.h>

#define N_NODES 100000
#define N_EDGES 1280000
#define DIM 64
#define N_GRAPHS 1000
#define BN_EPS 1e-5f
#define SCAN_BLOCKS 392   // 392*256 = 100352 >= N_NODES
#define WIN 128           // edges per wave window; N_EDGES/WIN = 10000 exactly
#define NWIN (N_EDGES / WIN)
#define GU 8              // edge unroll inside a window

// ---- bf16 helpers (top 16 bits of fp32, RTN pack) ----
__device__ __forceinline__ unsigned int bf16_rtn2(float a, float b) {
    unsigned int ua = __float_as_uint(a);
    unsigned int ub = __float_as_uint(b);
    ua = (ua + 0x7FFFu + ((ua >> 16) & 1u)) >> 16;
    ub = (ub + 0x7FFFu + ((ub >> 16) & 1u)) >> 16;
    return ua | (ub << 16);
}
__device__ __forceinline__ float bfup(unsigned short u) {
    return __uint_as_float(((unsigned int)u) << 16);
}

// ---------------- pass 1: degree histogram + per-edge rank + input BN stats ----------------
// 6000 blocks: 5-of-6 handle 256 edges each (5000 exactly covers 1.28M);
// 1-of-6 (1000 blocks) do the BN-input stats + per-graph node count.
// The atomicAdd RETURN VALUE is the edge's within-bucket rank -> no cursor pass later.
__global__ __launch_bounds__(256) void k_degstat(const int* __restrict__ ei,
                                                 const int* __restrict__ batch,
                                                 const float* __restrict__ X,
                                                 int* __restrict__ degc,
                                                 int* __restrict__ rk,
                                                 float* __restrict__ cnt,
                                                 float* __restrict__ gsum,
                                                 float* __restrict__ gsumsq) {
    int grp = blockIdx.x / 6, sl = blockIdx.x - grp * 6;
    if (sl < 5) {
        int e = (grp * 5 + sl) * 256 + threadIdx.x;
        rk[e] = atomicAdd(&degc[ei[N_EDGES + e]], 1);
        return;
    }
    // stats role (1000 blocks)
    int j = threadIdx.x & 63, rg = threadIdx.x >> 6;
    float s = 0.f, s2 = 0.f;
    for (int i = grp * 4 + rg; i < N_NODES; i += 4000) {
        float v = X[i * DIM + j];
        s += v; s2 += v * v;
        if (j == 0) atomicAdd(&cnt[batch[i]], 1.f);
    }
    __shared__ float ls[256], ls2[256];
    ls[threadIdx.x] = s; ls2[threadIdx.x] = s2;
    __syncthreads();
    if (threadIdx.x < 64) {
        s  = ls[j]  + ls[64 + j]  + ls[128 + j]  + ls[192 + j];
        s2 = ls2[j] + ls2[64 + j] + ls2[128 + j] + ls2[192 + j];
        atomicAdd(&gsum[j], s);
        atomicAdd(&gsumsq[j], s2);
    }
}

// ---------------- 3-step exclusive scan of deg -> rowstart ----------------
__global__ void k_scan1(const int* __restrict__ deg, int* __restrict__ iscan,
                        int* __restrict__ bsum) {
    __shared__ int ls[256];
    int i = blockIdx.x * 256 + threadIdx.x;
    int v = (i < N_NODES) ? deg[i] : 0;
    ls[threadIdx.x] = v;
    __syncthreads();
    for (int off = 1; off < 256; off <<= 1) {
        int t = (threadIdx.x >= off) ? ls[threadIdx.x - off] : 0;
        __syncthreads();
        ls[threadIdx.x] += t;
        __syncthreads();
    }
    if (i < N_NODES) iscan[i] = ls[threadIdx.x];
    if (threadIdx.x == 255) bsum[blockIdx.x] = ls[255];
}

__global__ void k_scan2(const int* __restrict__ bsum, int* __restrict__ boff) {
    __shared__ int ls[512];
    int t = threadIdx.x;
    int v0 = (t < SCAN_BLOCKS) ? bsum[t] : 0;
    ls[t] = v0;
    __syncthreads();
    for (int off = 1; off < 512; off <<= 1) {
        int v = (t >= off) ? ls[t - off] : 0;
        __syncthreads();
        ls[t] += v;
        __syncthreads();
    }
    if (t < SCAN_BLOCKS) boff[t] = ls[t] - v0;  // exclusive
}

// rowstart + dinv + winnode in one pass
__global__ void k_scan3(const int* __restrict__ deg, const int* __restrict__ iscan,
                        const int* __restrict__ boff, int* __restrict__ rowstart,
                        float* __restrict__ dinv, int* __restrict__ winnode) {
    int i = blockIdx.x * 256 + threadIdx.x;
    if (i < N_NODES) {
        int rs_end = boff[blockIdx.x] + iscan[i];
        int rs = rs_end - deg[i];
        rowstart[i] = rs;
        dinv[i] = 1.0f / sqrtf((float)(deg[i] + 1));
        // windows whose first edge lies in [rs, rs_end) are owned by node i
        for (int w = (rs + WIN - 1) / WIN; w * WIN < rs_end; ++w) winnode[w] = i;
    }
    if (i == 0) rowstart[N_NODES] = N_EDGES;
}

// place records: pos = rowstart[dst] + rank  (no atomics)
__global__ __launch_bounds__(256) void k_place(const int* __restrict__ ei,
                                               const int* __restrict__ rk,
                                               const int* __restrict__ rowstart,
                                               const float* __restrict__ dinv,
                                               int2* __restrict__ csr_ew) {
    int e = blockIdx.x * 256 + threadIdx.x;   // grid covers N_EDGES exactly
    int r = ei[e], c = ei[N_EDGES + e];
    int pos = rowstart[c] + rk[e];
    csr_ew[pos] = make_int2(r, (int)__float_as_uint(dinv[r] * dinv[c]));
}

// scale/shift + folded cshift in one single-block kernel
__global__ void k_bnfold(const float* __restrict__ gsum, const float* __restrict__ gsumsq,
                         const float* __restrict__ g, const float* __restrict__ b,
                         const float* __restrict__ W,
                         float* __restrict__ scale, float* __restrict__ cshift) {
    int j = threadIdx.x;
    float mean = gsum[j] * (1.0f / N_NODES);
    float var  = gsumsq[j] * (1.0f / N_NODES) - mean * mean;
    float inv  = 1.0f / sqrtf(var + BN_EPS);
    float sc   = g[j] * inv;
    scale[j] = sc;
    __shared__ float shl[64];
    shl[j] = b[j] - mean * sc;
    __syncthreads();
    float s = 0.f;
    for (int k = 0; k < DIM; k++) s += shl[k] * W[k * DIM + j];
    cshift[j] = s;
}

// plain BN coefficients (for the post-pool BN2)
__global__ void k_bnfinal(const float* __restrict__ gsum, const float* __restrict__ gsumsq,
                          const float* __restrict__ g, const float* __restrict__ b,
                          float* __restrict__ scale, float* __restrict__ shift) {
    int j = threadIdx.x;
    float mean = gsum[j] * (1.0f / N_NODES);
    float var  = gsumsq[j] * (1.0f / N_NODES) - mean * mean;
    float inv  = 1.0f / sqrtf(var + BN_EPS);
    float sc   = g[j] * inv;
    scale[j] = sc;
    shift[j] = b[j] - mean * sc;
}

// ---------------- GEMM: T(bf16) = (X*scale) @ W + cshift; also zero-inits C ----------------
__global__ __launch_bounds__(256) void k_gemm(const float* __restrict__ X,
                                              const float* __restrict__ W,
                                              const float* __restrict__ scale,
                                              const float* __restrict__ cshift,
                                              unsigned short* __restrict__ T,
                                              float* __restrict__ czero) {
    // strided zero of C (for the following gather's plain/atomic stores)
    float4 z4 = make_float4(0.f, 0.f, 0.f, 0.f);
    for (int t = blockIdx.x * 256 + threadIdx.x; t < N_NODES * (DIM / 4);
         t += gridDim.x * 256)
        ((float4*)czero)[t] = z4;

    __shared__ float Wl[64 * 64];
    __shared__ float Al[64 * 65];
    for (int t = threadIdx.x; t < 4096; t += 256) {
        int k = t >> 6;
        Wl[t] = W[t] * scale[k];
    }
    int row0 = blockIdx.x * 64;
    for (int t = threadIdx.x; t < 4096; t += 256) {
        int r = t >> 6, k = t & 63;
        int i = row0 + r;
        Al[r * 65 + k] = (i < N_NODES) ? X[i * DIM + k] : 0.f;
    }
    __syncthreads();

    int r = threadIdx.x & 63;
    int q = threadIdx.x >> 6;
    float acc[16];
    #pragma unroll
    for (int jj = 0; jj < 16; jj++) acc[jj] = cshift[q * 16 + jj];

    #pragma unroll 4
    for (int k = 0; k < 64; k++) {
        float a = Al[r * 65 + k];
        const float4* wv = (const float4*)&Wl[k * 64 + q * 16];
        float4 w0 = wv[0], w1 = wv[1], w2 = wv[2], w3 = wv[3];
        acc[0]  += a * w0.x; acc[1]  += a * w0.y; acc[2]  += a * w0.z; acc[3]  += a * w0.w;
        acc[4]  += a * w1.x; acc[5]  += a * w1.y; acc[6]  += a * w1.z; acc[7]  += a * w1.w;
        acc[8]  += a * w2.x; acc[9]  += a * w2.y; acc[10] += a * w2.z; acc[11] += a * w2.w;
        acc[12] += a * w3.x; acc[13] += a * w3.y; acc[14] += a * w3.z; acc[15] += a * w3.w;
    }
    int i = row0 + r;
    if (i < N_NODES) {
        unsigned int pk[8];
        #pragma unroll
        for (int jj = 0; jj < 8; jj++) pk[jj] = bf16_rtn2(acc[2 * jj], acc[2 * jj + 1]);
        uint4* outv = (uint4*)&T[(size_t)i * DIM + q * 16];
        outv[0] = make_uint4(pk[0], pk[1], pk[2], pk[3]);
        outv[1] = make_uint4(pk[4], pk[5], pk[6], pk[7]);
    }
}

// ---------------- edge-parallel gather: C[dst] += T[src]*w over a 128-edge window ----------
// wave = one window of WIN consecutive CSR edges; lane = feature.
// All row loads are fully coalesced (128 B, zero address divergence); 8 in flight.
// Node flushes: plain store if the node's edge range is inside the window,
// atomicAdd for the <=2 straddling nodes (C is pre-zeroed by k_gemm).
__global__ __launch_bounds__(256) void k_gather_ep(const unsigned short* __restrict__ T,
                                                   const int* __restrict__ rowstart,
                                                   const int* __restrict__ winnode,
                                                   const int2* __restrict__ csr_ew,
                                                   float* __restrict__ C,
                                                   float* __restrict__ gsum) {
    // block 0 zeros gsum/gsumsq for the following post kernel
    if (blockIdx.x == 0 && threadIdx.x < 128) gsum[threadIdx.x] = 0.f;
    int lane = threadIdx.x & 63;
    int w = blockIdx.x * 4 + (threadIdx.x >> 6);
    if (w >= NWIN) return;
    int e = w * WIN;
    const int eend = e + WIN;
    int i  = __builtin_amdgcn_readfirstlane(winnode[w]);
    int re = __builtin_amdgcn_readfirstlane(rowstart[i + 1]);
    bool part = __builtin_amdgcn_readfirstlane(rowstart[i]) < e;  // node started earlier
    float acc = 0.f;
    for (; e < eend; e += GU) {
        int   src[GU];
        float wt[GU];
        int eu = __builtin_amdgcn_readfirstlane(e);
        #pragma unroll
        for (int u = 0; u < GU; u++) {
            int2 ew = csr_ew[eu + u];            // wave-uniform -> scalar K$ loads
            src[u] = ew.x;
            wt[u]  = __uint_as_float((unsigned int)ew.y);
        }
        float tv[GU];
        #pragma unroll
        for (int u = 0; u < GU; u++)             // 8 independent coalesced 128B gathers
            tv[u] = bfup(T[(size_t)src[u] * DIM + lane]);
        #pragma unroll
        for (int u = 0; u < GU; u++) {
            while (e + u == re) {                // crossed into next node: flush i
                if (part) atomicAdd(&C[(size_t)i * DIM + lane], acc);
                else      C[(size_t)i * DIM + lane] = acc;
                acc = 0.f; part = false;
                ++i;
                re = __builtin_amdgcn_readfirstlane(rowstart[i + 1]);
            }
            acc += tv[u] * wt[u];
        }
    }
    // final flush: node complete at window end (re==eend) -> store, else partial -> atomic
    if (part || re > eend) atomicAdd(&C[(size_t)i * DIM + lane], acc);
    else                   C[(size_t)i * DIM + lane] = acc;
}

// ---------------- post layer 1: H = relu(C + self + bias), BN stats ----------------
__global__ __launch_bounds__(256) void k_post1(const float* __restrict__ C,
                                               const unsigned short* __restrict__ T,
                                               const float* __restrict__ dinv,
                                               const float* __restrict__ bias,
                                               float* __restrict__ H,
                                               float* __restrict__ gsum,
                                               float* __restrict__ gsumsq) {
    int lane = threadIdx.x & 63;
    int wv = threadIdx.x >> 6;
    int wid = blockIdx.x * 4 + wv;
    int nw = gridDim.x * 4;
    int per = (N_NODES + nw - 1) / nw;
    int i0 = wid * per, i1 = min(i0 + per, N_NODES);
    float bb = bias[lane];
    float s = 0.f, s2 = 0.f;
    for (int i = i0; i < i1; i++) {
        float di = dinv[i];
        float h = fmaxf(C[(size_t)i * DIM + lane]
                        + bfup(T[(size_t)i * DIM + lane]) * (di * di) + bb, 0.f);
        H[(size_t)i * DIM + lane] = h;
        s += h; s2 += h * h;
    }
    __shared__ float ls[256], ls2[256];
    ls[threadIdx.x] = s; ls2[threadIdx.x] = s2;
    __syncthreads();
    if (threadIdx.x < 64) {
        int j = threadIdx.x;
        float a  = ls[j]  + ls[64 + j]  + ls[128 + j]  + ls[192 + j];
        float a2 = ls2[j] + ls2[64 + j] + ls2[128 + j] + ls2[192 + j];
        atomicAdd(&gsum[j], a);
        atomicAdd(&gsumsq[j], a2);
    }
}

// ---------------- post layer 2: relu -> pool (run-flush) + BN stats ----------------
__global__ __launch_bounds__(256) void k_post2(const float* __restrict__ C,
                                               const unsigned short* __restrict__ T,
                                               const float* __restrict__ dinv,
                                               const float* __restrict__ bias,
                                               const int* __restrict__ batch,
                                               float* __restrict__ pool,
                                               float* __restrict__ gsum,
                                               float* __restrict__ gsumsq) {
    int lane = threadIdx.x & 63;
    int wv = threadIdx.x >> 6;
    int wid = blockIdx.x * 4 + wv;
    int nw = gridDim.x * 4;
    int per = (N_NODES + nw - 1) / nw;
    int i0 = wid * per, i1 = min(i0 + per, N_NODES);
    float bb = bias[lane];
    float s = 0.f, s2 = 0.f, ps = 0.f;
    int cur_g = -1;
    for (int i = i0; i < i1; i++) {
        float di = dinv[i];
        float h = fmaxf(C[(size_t)i * DIM + lane]
                        + bfup(T[(size_t)i * DIM + lane]) * (di * di) + bb, 0.f);
        s += h; s2 += h * h;
        int g = batch[i];                        // sorted -> rarely changes
        if (g != cur_g) {
            if (cur_g >= 0) atomicAdd(&pool[(size_t)cur_g * DIM + lane], ps);
            ps = 0.f; cur_g = g;
        }
        ps += h;
    }
    if (cur_g >= 0) atomicAdd(&pool[(size_t)cur_g * DIM + lane], ps);
    __shared__ float ls[256], ls2[256];
    ls[threadIdx.x] = s; ls2[threadIdx.x] = s2;
    __syncthreads();
    if (threadIdx.x < 64) {
        int j = threadIdx.x;
        float a  = ls[j]  + ls[64 + j]  + ls[128 + j]  + ls[192 + j];
        float a2 = ls2[j] + ls2[64 + j] + ls2[128 + j] + ls2[192 + j];
        atomicAdd(&gsum[j], a);
        atomicAdd(&gsumsq[j], a2);
    }
}

// ---------------- final: out[g] = ((pool/cnt)*scale + shift) @ Wout + bout ----------------
__global__ void k_final(const float* __restrict__ pool, const float* __restrict__ cnt,
                        const float* __restrict__ scale, const float* __restrict__ shift,
                        const float* __restrict__ Wout, const float* __restrict__ bout,
                        float* __restrict__ out) {
    int g = blockIdx.x;
    int l = threadIdx.x;
    float c = fmaxf(cnt[g], 1.f);
    float p = (pool[g * DIM + l] / c) * scale[l] + shift[l];
    float a0 = p * Wout[l * 2 + 0];
    float a1 = p * Wout[l * 2 + 1];
    #pragma unroll
    for (int off = 32; off; off >>= 1) {
        a0 += __shfl_down(a0, off, 64);
        a1 += __shfl_down(a1, off, 64);
    }
    if (l == 0) {
        out[g * 2 + 0] = a0 + bout[0];
        out[g * 2 + 1] = a1 + bout[1];
    }
}

extern "C" void kernel_launch(void* const* d_in, const int* in_sizes, int n_in,
                              void* d_out, int out_size, void* d_ws, size_t ws_size,
                              hipStream_t stream) {
    (void)in_sizes; (void)n_in; (void)out_size; (void)ws_size;
    const float* x       = (const float*)d_in[0];
    const int*   ei      = (const int*)d_in[1];
    const int*   batch   = (const int*)d_in[2];
    const float* bn_in_g = (const float*)d_in[3];
    const float* bn_in_b = (const float*)d_in[4];
    const float* W1      = (const float*)d_in[5];
    const float* b1      = (const float*)d_in[6];
    const float* g1      = (const float*)d_in[7];
    const float* be1     = (const float*)d_in[8];
    const float* W2      = (const float*)d_in[9];
    const float* b2      = (const float*)d_in[10];
    const float* g2      = (const float*)d_in[11];
    const float* be2     = (const float*)d_in[12];
    const float* Wout    = (const float*)d_in[13];
    const float* bout    = (const float*)d_in[14];
    float* out = (float*)d_out;

    // workspace layout (~77 MB), 8B alignment for csr_ew
    char* p = (char*)d_ws;
    float* H = (float*)p;                   p += (size_t)N_NODES * DIM * 4;  // 25.6 MB
    float* C = (float*)p;                   p += (size_t)N_NODES * DIM * 4;  // 25.6 MB
    unsigned short* T = (unsigned short*)p; p += (size_t)N_NODES * DIM * 2;  // 12.8 MB
    int2* csr_ew = (int2*)p;                p += (size_t)N_EDGES * 8;        // 10.24 MB
    float* dinv = (float*)p;                p += N_NODES * 4;
    int* degc = (int*)p;                    p += N_NODES * 4;
    float* gsum = (float*)p;                p += DIM * 4;   // degc|gsum|gsumsq contiguous
    float* gsumsq = (float*)p;              p += DIM * 4;   //   -> one memset clears all
    int* iscan = (int*)p;                   p += N_NODES * 4;
    int* rowstart = (int*)p;                p += (N_NODES + 2) * 4;
    int* winnode = (int*)p;                 p += NWIN * 4;                   // 40 KB
    int* bsum = (int*)p;                    p += SCAN_BLOCKS * 4;
    int* boff = (int*)p;                    p += SCAN_BLOCKS * 4;
    float* scale = (float*)p;               p += DIM * 4;
    float* shift = (float*)p;               p += DIM * 4;
    float* cshift = (float*)p;              p += DIM * 4;
    float* pool = (float*)p;                p += (size_t)N_GRAPHS * DIM * 4;
    float* cnt = (float*)p;                 p += N_GRAPHS * 4;
    int* rk = (int*)H;   // rank array aliases H: rk dead before k_post1 writes H

    // ---- CSR build (rank-from-atomic, no cursor pass) + BN-input stats ----
    hipMemsetAsync(degc, 0, N_NODES * sizeof(int) + 2 * DIM * sizeof(float), stream);
    hipMemsetAsync(pool, 0, (N_GRAPHS * DIM + N_GRAPHS) * sizeof(float), stream);
    k_degstat<<<6000, 256, 0, stream>>>(ei, batch, x, degc, rk, cnt, gsum, gsumsq);
    k_scan1<<<SCAN_BLOCKS, 256, 0, stream>>>(degc, iscan, bsum);
    k_scan2<<<1, 512, 0, stream>>>(bsum, boff);
    k_scan3<<<SCAN_BLOCKS, 256, 0, stream>>>(degc, iscan, boff, rowstart, dinv, winnode);
    k_place<<<N_EDGES / 256, 256, 0, stream>>>(ei, rk, rowstart, dinv, csr_ew);

    // ---- input BN -> GEMM1 (+C zero) -> edge-parallel gather -> post1 ----
    k_bnfold<<<1, 64, 0, stream>>>(gsum, gsumsq, bn_in_g, bn_in_b, W1, scale, cshift);
    k_gemm<<<(N_NODES + 63) / 64, 256, 0, stream>>>(x, W1, scale, cshift, T, C);
    k_gather_ep<<<NWIN / 4, 256, 0, stream>>>(T, rowstart, winnode, csr_ew, C, gsum);
    k_post1<<<1024, 256, 0, stream>>>(C, T, dinv, b1, H, gsum, gsumsq);

    // ---- BN1 -> GEMM2 (+C zero) -> gather -> post2 (pool+stats) ----
    k_bnfold<<<1, 64, 0, stream>>>(gsum, gsumsq, g1, be1, W2, scale, cshift);
    k_gemm<<<(N_NODES + 63) / 64, 256, 0, stream>>>(H, W2, scale, cshift, T, C);
    k_gather_ep<<<NWIN / 4, 256, 0, stream>>>(T, rowstart, winnode, csr_ew, C, gsum);
    k_post2<<<1024, 256, 0, stream>>>(C, T, dinv, b2, batch, pool, gsum, gsumsq);

    // ---- BN2 (post-pool; BN affine, pool linear) -> linear ----
    k_bnfinal<<<1, 64, 0, stream>>>(gsum, gsumsq, g2, be2, scale, shift);
    k_final<<<N_GRAPHS, 64, 0, stream>>>(pool, cnt, scale, shift, Wout, bout, out);
}

// Round 8
// 420.784 us; speedup vs baseline: 1.7262x; 1.2049x over previous
//
#include <hip/hip_runtime.h>
#include <math.h>

#define N_NODES 100000
#define N_EDGES 1280000
#define DIM 64
#define N_GRAPHS 1000
#define BN_EPS 1e-5f
#define NB 392            // buckets = dst>>8; 392*256 = 100352 >= N_NODES
#define P1B 256           // pass-1 blocks; 256*5000 = 1.28M exactly
#define P1E 5000          // edges per pass-1 block
#define WIN 128           // edges per gather wave window; N_EDGES/WIN = 10000
#define NWIN (N_EDGES / WIN)
#define GU 8              // edge unroll inside a window

// ---- bf16 helpers (top 16 bits of fp32, RTN pack) ----
__device__ __forceinline__ unsigned int bf16_rtn2(float a, float b) {
    unsigned int ua = __float_as_uint(a);
    unsigned int ub = __float_as_uint(b);
    ua = (ua + 0x7FFFu + ((ua >> 16) & 1u)) >> 16;
    ub = (ub + 0x7FFFu + ((ub >> 16) & 1u)) >> 16;
    return ua | (ub << 16);
}
__device__ __forceinline__ float bfup(unsigned short u) {
    return __uint_as_float(((unsigned int)u) << 16);
}

// ---------------- pass 1a: bucket histograms (LDS) + input BN stats + graph starts ----------
// blocks [0,256): LDS histogram of dst>>8 over 5000 edges -> bh[bucket*256+blk]
// blocks [256,1256): BN-input stats over X + graph-boundary scatter (batch is sorted)
__global__ __launch_bounds__(256) void k_p1hist(const int* __restrict__ ei,
                                                const int* __restrict__ batch,
                                                const float* __restrict__ X,
                                                int* __restrict__ bh,
                                                int* __restrict__ start,
                                                float* __restrict__ gsum,
                                                float* __restrict__ gsumsq) {
    int t = threadIdx.x;
    if (blockIdx.x < P1B) {
        __shared__ int hist[NB];
        for (int b = t; b < NB; b += 256) hist[b] = 0;
        __syncthreads();
        int e0 = blockIdx.x * P1E;
        for (int e = e0 + t; e < e0 + P1E; e += 256)
            atomicAdd(&hist[ei[N_EDGES + e] >> 8], 1);
        __syncthreads();
        for (int b = t; b < NB; b += 256) bh[b * P1B + blockIdx.x] = hist[b];
        return;
    }
    int grp = blockIdx.x - P1B;           // 0..999
    int j = t & 63, rg = t >> 6;
    float s = 0.f, s2 = 0.f;
    for (int i = grp * 4 + rg; i < N_NODES; i += 4000) {
        float v = X[i * DIM + j];
        s += v; s2 += v * v;
        if (j == 0) {
            int g = batch[i];
            if (i == 0) { for (int q = 0; q <= g; q++) start[q] = 0; }
            else {
                int gp = batch[i - 1];
                for (int q = gp + 1; q <= g; q++) start[q] = i;
            }
            if (i == N_NODES - 1)
                for (int q = g + 1; q <= N_GRAPHS; q++) start[q] = N_NODES;
        }
    }
    __shared__ float ls[256], ls2[256];
    ls[t] = s; ls2[t] = s2;
    __syncthreads();
    if (t < 64) {
        s  = ls[j]  + ls[64 + j]  + ls[128 + j]  + ls[192 + j];
        s2 = ls2[j] + ls2[64 + j] + ls2[128 + j] + ls2[192 + j];
        atomicAdd(&gsum[j], s);
        atomicAdd(&gsumsq[j], s2);
    }
}

// ---------------- scan of bh[100352] (bucket-major) ----------------
__global__ void k_scan1(const int* __restrict__ bh, int* __restrict__ iscan,
                        int* __restrict__ bsum) {
    __shared__ int ls[256];
    int i = blockIdx.x * 256 + threadIdx.x;
    int v = bh[i];
    ls[threadIdx.x] = v;
    __syncthreads();
    for (int off = 1; off < 256; off <<= 1) {
        int tv = (threadIdx.x >= off) ? ls[threadIdx.x - off] : 0;
        __syncthreads();
        ls[threadIdx.x] += tv;
        __syncthreads();
    }
    iscan[i] = ls[threadIdx.x];
    if (threadIdx.x == 255) bsum[blockIdx.x] = ls[255];
}

__global__ void k_scan2(const int* __restrict__ bsum, int* __restrict__ boff) {
    __shared__ int ls[512];
    int t = threadIdx.x;
    int v0 = (t < NB) ? bsum[t] : 0;
    ls[t] = v0;
    __syncthreads();
    for (int off = 1; off < 512; off <<= 1) {
        int v = (t >= off) ? ls[t - off] : 0;
        __syncthreads();
        ls[t] += v;
        __syncthreads();
    }
    if (t < NB) boff[t] = ls[t] - v0;  // exclusive over scan-blocks (== buckets)
}

// ---------------- pass 1b: scatter edges into bucket-major tmp (no global atomics) --------
__global__ __launch_bounds__(256) void k_p1scat(const int* __restrict__ ei,
                                                const int* __restrict__ bh,
                                                const int* __restrict__ iscan,
                                                const int* __restrict__ boff,
                                                int2* __restrict__ tmp) {
    __shared__ int cur[NB];
    int blk = blockIdx.x;
    for (int b = threadIdx.x; b < NB; b += 256) {
        int i = b * P1B + blk;             // i>>8 == b (bucket-major, P1B==256)
        cur[b] = boff[b] + iscan[i] - bh[i];
    }
    __syncthreads();
    int e0 = blk * P1E;
    for (int e = e0 + threadIdx.x; e < e0 + P1E; e += 256) {
        int r = ei[e], c = ei[N_EDGES + e];
        int pos = atomicAdd(&cur[c >> 8], 1);   // LDS atomic
        tmp[pos] = make_int2(r, c);
    }
}

// ---------------- pass 2a: per-bucket histogram -> dinv, rowstart, winnode ----------------
__global__ __launch_bounds__(256) void k_p2a(const int2* __restrict__ tmp,
                                             const int* __restrict__ bh,
                                             const int* __restrict__ iscan,
                                             const int* __restrict__ boff,
                                             int* __restrict__ rowstart,
                                             float* __restrict__ dinv,
                                             int* __restrict__ winnode) {
    int b = blockIdx.x, t = threadIdx.x;
    int bstart = boff[b] + iscan[b * 256] - bh[b * 256];
    int bend = (b == NB - 1) ? N_EDGES
                             : (boff[b + 1] + iscan[(b + 1) * 256] - bh[(b + 1) * 256]);
    __shared__ int cnt[256], scn[256];
    cnt[t] = 0;
    __syncthreads();
    for (int e = bstart + t; e < bend; e += 256)
        atomicAdd(&cnt[tmp[e].y & 255], 1);
    __syncthreads();
    scn[t] = cnt[t];
    __syncthreads();
    for (int off = 1; off < 256; off <<= 1) {
        int v = (t >= off) ? scn[t - off] : 0;
        __syncthreads();
        scn[t] += v;
        __syncthreads();
    }
    int node = b * 256 + t;
    int rs = bstart + scn[t] - cnt[t];       // exclusive
    if (node <= N_NODES) rowstart[node] = rs;
    if (node < N_NODES) {
        int deg = cnt[t];
        dinv[node] = 1.0f / sqrtf((float)(deg + 1));
        int re = rs + deg;
        for (int w = (rs + WIN - 1) / WIN; w * WIN < re; ++w) winnode[w] = node;
    }
}

// ---------------- pass 2b: within-bucket sort + weights -> final CSR ----------------
__global__ __launch_bounds__(256) void k_p2b(const int2* __restrict__ tmp,
                                             const int* __restrict__ bh,
                                             const int* __restrict__ iscan,
                                             const int* __restrict__ boff,
                                             const int* __restrict__ rowstart,
                                             const float* __restrict__ dinv,
                                             int2* __restrict__ csr_ew) {
    int b = blockIdx.x, t = threadIdx.x;
    int bstart = boff[b] + iscan[b * 256] - bh[b * 256];
    int bend = (b == NB - 1) ? N_EDGES
                             : (boff[b + 1] + iscan[(b + 1) * 256] - bh[(b + 1) * 256]);
    __shared__ int curs[256];
    __shared__ float dl[256];
    int node = b * 256 + t;
    curs[t] = (node < N_NODES) ? rowstart[node] : 0;
    dl[t]   = (node < N_NODES) ? dinv[node] : 0.f;
    __syncthreads();
    for (int e = bstart + t; e < bend; e += 256) {
        int2 rec = tmp[e];
        int ld = rec.y & 255;
        int pos = atomicAdd(&curs[ld], 1);   // LDS atomic
        float w = dl[ld] * dinv[rec.x];
        csr_ew[pos] = make_int2(rec.x, (int)__float_as_uint(w));
    }
}

// scale/shift + folded cshift in one single-block kernel
__global__ void k_bnfold(const float* __restrict__ gsum, const float* __restrict__ gsumsq,
                         const float* __restrict__ g, const float* __restrict__ b,
                         const float* __restrict__ W,
                         float* __restrict__ scale, float* __restrict__ cshift) {
    int j = threadIdx.x;
    float mean = gsum[j] * (1.0f / N_NODES);
    float var  = gsumsq[j] * (1.0f / N_NODES) - mean * mean;
    float inv  = 1.0f / sqrtf(var + BN_EPS);
    float sc   = g[j] * inv;
    scale[j] = sc;
    __shared__ float shl[64];
    shl[j] = b[j] - mean * sc;
    __syncthreads();
    float s = 0.f;
    for (int k = 0; k < DIM; k++) s += shl[k] * W[k * DIM + j];
    cshift[j] = s;
}

// plain BN coefficients (for the post-pool BN2)
__global__ void k_bnfinal(const float* __restrict__ gsum, const float* __restrict__ gsumsq,
                          const float* __restrict__ g, const float* __restrict__ b,
                          float* __restrict__ scale, float* __restrict__ shift) {
    int j = threadIdx.x;
    float mean = gsum[j] * (1.0f / N_NODES);
    float var  = gsumsq[j] * (1.0f / N_NODES) - mean * mean;
    float inv  = 1.0f / sqrtf(var + BN_EPS);
    float sc   = g[j] * inv;
    scale[j] = sc;
    shift[j] = b[j] - mean * sc;
}

// ---------------- GEMM: T(bf16) = (X*scale) @ W + cshift; also zero-inits C ----------------
__global__ __launch_bounds__(256) void k_gemm(const float* __restrict__ X,
                                              const float* __restrict__ W,
                                              const float* __restrict__ scale,
                                              const float* __restrict__ cshift,
                                              unsigned short* __restrict__ T,
                                              float* __restrict__ czero) {
    float4 z4 = make_float4(0.f, 0.f, 0.f, 0.f);
    for (int t = blockIdx.x * 256 + threadIdx.x; t < N_NODES * (DIM / 4);
         t += gridDim.x * 256)
        ((float4*)czero)[t] = z4;

    __shared__ float Wl[64 * 64];
    __shared__ float Al[64 * 65];
    for (int t = threadIdx.x; t < 4096; t += 256) {
        int k = t >> 6;
        Wl[t] = W[t] * scale[k];
    }
    int row0 = blockIdx.x * 64;
    for (int t = threadIdx.x; t < 4096; t += 256) {
        int r = t >> 6, k = t & 63;
        int i = row0 + r;
        Al[r * 65 + k] = (i < N_NODES) ? X[i * DIM + k] : 0.f;
    }
    __syncthreads();

    int r = threadIdx.x & 63;
    int q = threadIdx.x >> 6;
    float acc[16];
    #pragma unroll
    for (int jj = 0; jj < 16; jj++) acc[jj] = cshift[q * 16 + jj];

    #pragma unroll 4
    for (int k = 0; k < 64; k++) {
        float a = Al[r * 65 + k];
        const float4* wv = (const float4*)&Wl[k * 64 + q * 16];
        float4 w0 = wv[0], w1 = wv[1], w2 = wv[2], w3 = wv[3];
        acc[0]  += a * w0.x; acc[1]  += a * w0.y; acc[2]  += a * w0.z; acc[3]  += a * w0.w;
        acc[4]  += a * w1.x; acc[5]  += a * w1.y; acc[6]  += a * w1.z; acc[7]  += a * w1.w;
        acc[8]  += a * w2.x; acc[9]  += a * w2.y; acc[10] += a * w2.z; acc[11] += a * w2.w;
        acc[12] += a * w3.x; acc[13] += a * w3.y; acc[14] += a * w3.z; acc[15] += a * w3.w;
    }
    int i = row0 + r;
    if (i < N_NODES) {
        unsigned int pk[8];
        #pragma unroll
        for (int jj = 0; jj < 8; jj++) pk[jj] = bf16_rtn2(acc[2 * jj], acc[2 * jj + 1]);
        uint4* outv = (uint4*)&T[(size_t)i * DIM + q * 16];
        outv[0] = make_uint4(pk[0], pk[1], pk[2], pk[3]);
        outv[1] = make_uint4(pk[4], pk[5], pk[6], pk[7]);
    }
}

// ---------------- edge-parallel gather: C[dst] += T[src]*w over a 128-edge window ----------
__global__ __launch_bounds__(256) void k_gather_ep(const unsigned short* __restrict__ T,
                                                   const int* __restrict__ rowstart,
                                                   const int* __restrict__ winnode,
                                                   const int2* __restrict__ csr_ew,
                                                   float* __restrict__ C,
                                                   float* __restrict__ gsum) {
    if (blockIdx.x == 0 && threadIdx.x < 128) gsum[threadIdx.x] = 0.f;
    int lane = threadIdx.x & 63;
    int w = blockIdx.x * 4 + (threadIdx.x >> 6);
    if (w >= NWIN) return;
    int e = w * WIN;
    const int eend = e + WIN;
    int i  = __builtin_amdgcn_readfirstlane(winnode[w]);
    int re = __builtin_amdgcn_readfirstlane(rowstart[i + 1]);
    bool part = __builtin_amdgcn_readfirstlane(rowstart[i]) < e;
    float acc = 0.f;
    for (; e < eend; e += GU) {
        int   src[GU];
        float wt[GU];
        int eu = __builtin_amdgcn_readfirstlane(e);
        #pragma unroll
        for (int u = 0; u < GU; u++) {
            int2 ew = csr_ew[eu + u];
            src[u] = ew.x;
            wt[u]  = __uint_as_float((unsigned int)ew.y);
        }
        float tv[GU];
        #pragma unroll
        for (int u = 0; u < GU; u++)
            tv[u] = bfup(T[(size_t)src[u] * DIM + lane]);
        #pragma unroll
        for (int u = 0; u < GU; u++) {
            while (e + u == re) {
                if (part) atomicAdd(&C[(size_t)i * DIM + lane], acc);
                else      C[(size_t)i * DIM + lane] = acc;
                acc = 0.f; part = false;
                ++i;
                re = __builtin_amdgcn_readfirstlane(rowstart[i + 1]);
            }
            acc += tv[u] * wt[u];
        }
    }
    if (part || re > eend) atomicAdd(&C[(size_t)i * DIM + lane], acc);
    else                   C[(size_t)i * DIM + lane] = acc;
}

// ---------------- post layer 1: H = relu(C + self + bias), BN stats ----------------
__global__ __launch_bounds__(256) void k_post1(const float* __restrict__ C,
                                               const unsigned short* __restrict__ T,
                                               const float* __restrict__ dinv,
                                               const float* __restrict__ bias,
                                               float* __restrict__ H,
                                               float* __restrict__ gsum,
                                               float* __restrict__ gsumsq) {
    int lane = threadIdx.x & 63;
    int wv = threadIdx.x >> 6;
    int wid = blockIdx.x * 4 + wv;
    int nw = gridDim.x * 4;
    int per = (N_NODES + nw - 1) / nw;
    int i0 = wid * per, i1 = min(i0 + per, N_NODES);
    float bb = bias[lane];
    float s = 0.f, s2 = 0.f;
    for (int i = i0; i < i1; i++) {
        float di = dinv[i];
        float h = fmaxf(C[(size_t)i * DIM + lane]
                        + bfup(T[(size_t)i * DIM + lane]) * (di * di) + bb, 0.f);
        H[(size_t)i * DIM + lane] = h;
        s += h; s2 += h * h;
    }
    __shared__ float ls[256], ls2[256];
    ls[threadIdx.x] = s; ls2[threadIdx.x] = s2;
    __syncthreads();
    if (threadIdx.x < 64) {
        int j = threadIdx.x;
        float a  = ls[j]  + ls[64 + j]  + ls[128 + j]  + ls[192 + j];
        float a2 = ls2[j] + ls2[64 + j] + ls2[128 + j] + ls2[192 + j];
        atomicAdd(&gsum[j], a);
        atomicAdd(&gsumsq[j], a2);
    }
}

// ---------------- post layer 2: relu -> pool (run-flush) + BN stats ----------------
__global__ __launch_bounds__(256) void k_post2(const float* __restrict__ C,
                                               const unsigned short* __restrict__ T,
                                               const float* __restrict__ dinv,
                                               const float* __restrict__ bias,
                                               const int* __restrict__ batch,
                                               float* __restrict__ pool,
                                               float* __restrict__ gsum,
                                               float* __restrict__ gsumsq) {
    int lane = threadIdx.x & 63;
    int wv = threadIdx.x >> 6;
    int wid = blockIdx.x * 4 + wv;
    int nw = gridDim.x * 4;
    int per = (N_NODES + nw - 1) / nw;
    int i0 = wid * per, i1 = min(i0 + per, N_NODES);
    float bb = bias[lane];
    float s = 0.f, s2 = 0.f, ps = 0.f;
    int cur_g = -1;
    for (int i = i0; i < i1; i++) {
        float di = dinv[i];
        float h = fmaxf(C[(size_t)i * DIM + lane]
                        + bfup(T[(size_t)i * DIM + lane]) * (di * di) + bb, 0.f);
        s += h; s2 += h * h;
        int g = batch[i];
        if (g != cur_g) {
            if (cur_g >= 0) atomicAdd(&pool[(size_t)cur_g * DIM + lane], ps);
            ps = 0.f; cur_g = g;
        }
        ps += h;
    }
    if (cur_g >= 0) atomicAdd(&pool[(size_t)cur_g * DIM + lane], ps);
    __shared__ float ls[256], ls2[256];
    ls[threadIdx.x] = s; ls2[threadIdx.x] = s2;
    __syncthreads();
    if (threadIdx.x < 64) {
        int j = threadIdx.x;
        float a  = ls[j]  + ls[64 + j]  + ls[128 + j]  + ls[192 + j];
        float a2 = ls2[j] + ls2[64 + j] + ls2[128 + j] + ls2[192 + j];
        atomicAdd(&gsum[j], a);
        atomicAdd(&gsumsq[j], a2);
    }
}

// ---------------- final: out[g] = ((pool/cnt)*scale + shift) @ Wout + bout ----------------
__global__ void k_final(const float* __restrict__ pool, const int* __restrict__ start,
                        const float* __restrict__ scale, const float* __restrict__ shift,
                        const float* __restrict__ Wout, const float* __restrict__ bout,
                        float* __restrict__ out) {
    int g = blockIdx.x;
    int l = threadIdx.x;
    float c = fmaxf((float)(start[g + 1] - start[g]), 1.f);
    float p = (pool[g * DIM + l] / c) * scale[l] + shift[l];
    float a0 = p * Wout[l * 2 + 0];
    float a1 = p * Wout[l * 2 + 1];
    #pragma unroll
    for (int off = 32; off; off >>= 1) {
        a0 += __shfl_down(a0, off, 64);
        a1 += __shfl_down(a1, off, 64);
    }
    if (l == 0) {
        out[g * 2 + 0] = a0 + bout[0];
        out[g * 2 + 1] = a1 + bout[1];
    }
}

extern "C" void kernel_launch(void* const* d_in, const int* in_sizes, int n_in,
                              void* d_out, int out_size, void* d_ws, size_t ws_size,
                              hipStream_t stream) {
    (void)in_sizes; (void)n_in; (void)out_size; (void)ws_size;
    const float* x       = (const float*)d_in[0];
    const int*   ei      = (const int*)d_in[1];
    const int*   batch   = (const int*)d_in[2];
    const float* bn_in_g = (const float*)d_in[3];
    const float* bn_in_b = (const float*)d_in[4];
    const float* W1      = (const float*)d_in[5];
    const float* b1      = (const float*)d_in[6];
    const float* g1      = (const float*)d_in[7];
    const float* be1     = (const float*)d_in[8];
    const float* W2      = (const float*)d_in[9];
    const float* b2      = (const float*)d_in[10];
    const float* g2      = (const float*)d_in[11];
    const float* be2     = (const float*)d_in[12];
    const float* Wout    = (const float*)d_in[13];
    const float* bout    = (const float*)d_in[14];
    float* out = (float*)d_out;

    // workspace layout (~77 MB), 8B alignment for int2 arrays
    char* p = (char*)d_ws;
    float* H = (float*)p;                   p += (size_t)N_NODES * DIM * 4;  // 25.6 MB
    float* C = (float*)p;                   p += (size_t)N_NODES * DIM * 4;  // 25.6 MB
    unsigned short* T = (unsigned short*)p; p += (size_t)N_NODES * DIM * 2;  // 12.8 MB
    int2* csr_ew = (int2*)p;                p += (size_t)N_EDGES * 8;        // 10.24 MB
    float* dinv = (float*)p;                p += N_NODES * 4;
    int* bh = (int*)p;                      p += NB * P1B * 4;               // 100352 ints
    int* iscan = (int*)p;                   p += NB * P1B * 4;
    int* rowstart = (int*)p;                p += (N_NODES + 2) * 4;
    int* winnode = (int*)p;                 p += NWIN * 4;                   // 40 KB
    int* bsum = (int*)p;                    p += NB * 4;
    int* boff = (int*)p;                    p += NB * 4;
    int* start = (int*)p;                   p += (N_GRAPHS + 2) * 4;
    float* gsum = (float*)p;                p += DIM * 4;   // gsum|gsumsq contiguous
    float* gsumsq = (float*)p;              p += DIM * 4;
    float* scale = (float*)p;               p += DIM * 4;
    float* shift = (float*)p;               p += DIM * 4;
    float* cshift = (float*)p;              p += DIM * 4;
    float* pool = (float*)p;                p += (size_t)N_GRAPHS * DIM * 4;
    int2* tmp = (int2*)H;  // pass-1 output aliases H (dead before k_post1 writes H)

    // ---- CSR build: 2-pass bucket sort, LDS atomics only ----
    hipMemsetAsync(gsum, 0, 2 * DIM * sizeof(float), stream);
    hipMemsetAsync(pool, 0, (size_t)N_GRAPHS * DIM * sizeof(float), stream);
    k_p1hist<<<P1B + 1000, 256, 0, stream>>>(ei, batch, x, bh, start, gsum, gsumsq);
    k_scan1<<<NB, 256, 0, stream>>>(bh, iscan, bsum);
    k_scan2<<<1, 512, 0, stream>>>(bsum, boff);
    k_p1scat<<<P1B, 256, 0, stream>>>(ei, bh, iscan, boff, tmp);
    k_p2a<<<NB, 256, 0, stream>>>(tmp, bh, iscan, boff, rowstart, dinv, winnode);
    k_p2b<<<NB, 256, 0, stream>>>(tmp, bh, iscan, boff, rowstart, dinv, csr_ew);

    // ---- input BN -> GEMM1 (+C zero) -> edge-parallel gather -> post1 ----
    k_bnfold<<<1, 64, 0, stream>>>(gsum, gsumsq, bn_in_g, bn_in_b, W1, scale, cshift);
    k_gemm<<<(N_NODES + 63) / 64, 256, 0, stream>>>(x, W1, scale, cshift, T, C);
    k_gather_ep<<<NWIN / 4, 256, 0, stream>>>(T, rowstart, winnode, csr_ew, C, gsum);
    k_post1<<<1024, 256, 0, stream>>>(C, T, dinv, b1, H, gsum, gsumsq);

    // ---- BN1 -> GEMM2 (+C zero) -> gather -> post2 (pool+stats) ----
    k_bnfold<<<1, 64, 0, stream>>>(gsum, gsumsq, g1, be1, W2, scale, cshift);
    k_gemm<<<(N_NODES + 63) / 64, 256, 0, stream>>>(H, W2, scale, cshift, T, C);
    k_gather_ep<<<NWIN / 4, 256, 0, stream>>>(T, rowstart, winnode, csr_ew, C, gsum);
    k_post2<<<1024, 256, 0, stream>>>(C, T, dinv, b2, batch, pool, gsum, gsumsq);

    // ---- BN2 (post-pool; BN affine, pool linear) -> linear ----
    k_bnfinal<<<1, 64, 0, stream>>>(gsum, gsumsq, g2, be2, scale, shift);
    k_final<<<N_GRAPHS, 64, 0, stream>>>(pool, start, scale, shift, Wout, bout, out);
}

// Round 9
// 353.444 us; speedup vs baseline: 2.0551x; 1.1905x over previous
//
#include <hip/hip_runtime.h>
#include <math.h>

#define N_NODES 100000
#define N_EDGES 1280000
#define DIM 64
#define N_GRAPHS 1000
#define BN_EPS 1e-5f
#define NB 392            // buckets = dst>>8; 392*256 = 100352 >= N_NODES
#define P1B 256           // pass-1 histogram blocks; 256*5000 = 1.28M exactly
#define P1E 5000
#define SB 400            // stats blocks (400*250 = 100k rows, contiguous spans)
#define WIN 128           // edges per gather wave window; N_EDGES/WIN = 10000
#define NWIN (N_EDGES / WIN)
#define GU 8
#define NSLOT 32          // BN-stat partial slots (contention /32)

// ---- bf16 helpers (top 16 bits of fp32, RTN) ----
__device__ __forceinline__ unsigned int bf16_rtn2(float a, float b) {
    unsigned int ua = __float_as_uint(a);
    unsigned int ub = __float_as_uint(b);
    ua = (ua + 0x7FFFu + ((ua >> 16) & 1u)) >> 16;
    ub = (ub + 0x7FFFu + ((ub >> 16) & 1u)) >> 16;
    return ua | (ub << 16);
}
__device__ __forceinline__ unsigned short bf16r(float a) {
    unsigned int u = __float_as_uint(a);
    return (unsigned short)((u + 0x7FFFu + ((u >> 16) & 1u)) >> 16);
}
__device__ __forceinline__ float bfup(unsigned short u) {
    return __uint_as_float(((unsigned int)u) << 16);
}

// ---------------- pass 1a: histogram + BN-input stats + graph boundaries ----------------
// blocks [0,256): LDS histogram of dst>>8 over 5000 edges -> bh[bucket*256+blk]
// blocks [256,656): BN stats over contiguous 250-row spans of X
// blocks [656,1048): graph-start boundary scatter (batch sorted, coalesced)
__global__ __launch_bounds__(256) void k_p1hist(const int* __restrict__ ei,
                                                const int* __restrict__ batch,
                                                const float* __restrict__ X,
                                                int* __restrict__ bh,
                                                int* __restrict__ start,
                                                float* __restrict__ gsum,
                                                float* __restrict__ gsumsq) {
    int t = threadIdx.x;
    if (blockIdx.x < P1B) {
        __shared__ int hist[NB];
        for (int b = t; b < NB; b += 256) hist[b] = 0;
        __syncthreads();
        int e0 = blockIdx.x * P1E;
        #pragma unroll 4
        for (int e = e0 + t; e < e0 + P1E; e += 256)
            atomicAdd(&hist[ei[N_EDGES + e] >> 8], 1);
        __syncthreads();
        for (int b = t; b < NB; b += 256) bh[b * P1B + blockIdx.x] = hist[b];
    } else if (blockIdx.x < P1B + SB) {
        int grp = blockIdx.x - P1B;
        int j = t & 63, rg = t >> 6;
        int base = grp * 250;
        float s = 0.f, s2 = 0.f;
        for (int i = base + rg; i < base + 250; i += 4) {
            float v = X[i * DIM + j];
            s += v; s2 += v * v;
        }
        __shared__ float ls[256], ls2[256];
        ls[t] = s; ls2[t] = s2;
        __syncthreads();
        if (t < 64) {
            int slot = (grp & (NSLOT - 1)) * DIM;
            s  = ls[j]  + ls[64 + j]  + ls[128 + j]  + ls[192 + j];
            s2 = ls2[j] + ls2[64 + j] + ls2[128 + j] + ls2[192 + j];
            atomicAdd(&gsum[slot + j], s);
            atomicAdd(&gsumsq[slot + j], s2);
        }
    } else {
        int i = (blockIdx.x - P1B - SB) * 256 + t;
        if (i < N_NODES) {
            int cur = batch[i];
            if (i == 0) { for (int q = 0; q <= cur; q++) start[q] = 0; }
            else {
                int prev = batch[i - 1];
                for (int q = prev + 1; q <= cur; q++) start[q] = i;
            }
            if (i == N_NODES - 1)
                for (int q = cur + 1; q <= N_GRAPHS; q++) start[q] = N_NODES;
        }
    }
}

// ---------------- scan of bh[100352] ----------------
__global__ void k_scan1(const int* __restrict__ bh, int* __restrict__ iscan,
                        int* __restrict__ bsum) {
    __shared__ int ls[256];
    int i = blockIdx.x * 256 + threadIdx.x;
    int v = bh[i];
    ls[threadIdx.x] = v;
    __syncthreads();
    for (int off = 1; off < 256; off <<= 1) {
        int tv = (threadIdx.x >= off) ? ls[threadIdx.x - off] : 0;
        __syncthreads();
        ls[threadIdx.x] += tv;
        __syncthreads();
    }
    iscan[i] = ls[threadIdx.x];
    if (threadIdx.x == 255) bsum[blockIdx.x] = ls[255];
}

__global__ void k_scan2(const int* __restrict__ bsum, int* __restrict__ boff) {
    __shared__ int ls[512];
    int t = threadIdx.x;
    int v0 = (t < NB) ? bsum[t] : 0;
    ls[t] = v0;
    __syncthreads();
    for (int off = 1; off < 512; off <<= 1) {
        int v = (t >= off) ? ls[t - off] : 0;
        __syncthreads();
        ls[t] += v;
        __syncthreads();
    }
    if (t < NB) boff[t] = ls[t] - v0;
}

// ---------------- pass 1b: scatter into bucket-major tmp (LDS cursors) ----------------
__global__ __launch_bounds__(256) void k_p1scat(const int* __restrict__ ei,
                                                const int* __restrict__ bh,
                                                const int* __restrict__ iscan,
                                                const int* __restrict__ boff,
                                                int2* __restrict__ tmp) {
    __shared__ int cur[NB];
    int blk = blockIdx.x;
    for (int b = threadIdx.x; b < NB; b += 256) {
        int i = b * P1B + blk;
        cur[b] = boff[b] + iscan[i] - bh[i];
    }
    __syncthreads();
    int e0 = blk * P1E;
    for (int e = e0 + threadIdx.x; e < e0 + P1E; e += 256) {
        int r = ei[e], c = ei[N_EDGES + e];
        int pos = atomicAdd(&cur[c >> 8], 1);
        tmp[pos] = make_int2(r, c);
    }
}

// ---------------- pass 2a: per-bucket histogram -> dinv, rowstart, winnode --------------
__global__ __launch_bounds__(256) void k_p2a(const int2* __restrict__ tmp,
                                             const int* __restrict__ bh,
                                             const int* __restrict__ iscan,
                                             const int* __restrict__ boff,
                                             int* __restrict__ rowstart,
                                             float* __restrict__ dinv,
                                             int* __restrict__ winnode) {
    int b = blockIdx.x, t = threadIdx.x;
    int bstart = boff[b] + iscan[b * 256] - bh[b * 256];
    int bend = (b == NB - 1) ? N_EDGES
                             : (boff[b + 1] + iscan[(b + 1) * 256] - bh[(b + 1) * 256]);
    __shared__ int cnt[256], scn[256];
    cnt[t] = 0;
    __syncthreads();
    for (int e = bstart + t; e < bend; e += 256)
        atomicAdd(&cnt[tmp[e].y & 255], 1);
    __syncthreads();
    scn[t] = cnt[t];
    __syncthreads();
    for (int off = 1; off < 256; off <<= 1) {
        int v = (t >= off) ? scn[t - off] : 0;
        __syncthreads();
        scn[t] += v;
        __syncthreads();
    }
    int node = b * 256 + t;
    int rs = bstart + scn[t] - cnt[t];
    if (node <= N_NODES) rowstart[node] = rs;
    if (node < N_NODES) {
        int deg = cnt[t];
        dinv[node] = 1.0f / sqrtf((float)(deg + 1));
        int re = rs + deg;
        for (int w = (rs + WIN - 1) / WIN; w * WIN < re; ++w) winnode[w] = node;
    }
}

// ---------------- pass 2b: within-bucket sort + weights -> final CSR ----------------
__global__ __launch_bounds__(256) void k_p2b(const int2* __restrict__ tmp,
                                             const int* __restrict__ bh,
                                             const int* __restrict__ iscan,
                                             const int* __restrict__ boff,
                                             const int* __restrict__ rowstart,
                                             const float* __restrict__ dinv,
                                             int2* __restrict__ csr_ew) {
    int b = blockIdx.x, t = threadIdx.x;
    int bstart = boff[b] + iscan[b * 256] - bh[b * 256];
    int bend = (b == NB - 1) ? N_EDGES
                             : (boff[b + 1] + iscan[(b + 1) * 256] - bh[(b + 1) * 256]);
    __shared__ int curs[256];
    __shared__ float dl[256];
    int node = b * 256 + t;
    curs[t] = (node < N_NODES) ? rowstart[node] : 0;
    dl[t]   = (node < N_NODES) ? dinv[node] : 0.f;
    __syncthreads();
    for (int e = bstart + t; e < bend; e += 256) {
        int2 rec = tmp[e];
        int ld = rec.y & 255;
        int pos = atomicAdd(&curs[ld], 1);
        float w = dl[ld] * dinv[rec.x];
        csr_ew[pos] = make_int2(rec.x, (int)__float_as_uint(w));
    }
}

// ---------------- BN fold: reduce 32 slots, compute scale/cshift, re-zero slots ---------
__global__ void k_bnfold(float* __restrict__ gsum, float* __restrict__ gsumsq,
                         const float* __restrict__ g, const float* __restrict__ b,
                         const float* __restrict__ W,
                         float* __restrict__ scale, float* __restrict__ cshift) {
    int j = threadIdx.x;
    float ms = 0.f, m2 = 0.f;
    for (int k = 0; k < NSLOT; k++) {
        ms += gsum[k * DIM + j];   gsum[k * DIM + j] = 0.f;
        m2 += gsumsq[k * DIM + j]; gsumsq[k * DIM + j] = 0.f;
    }
    float mean = ms * (1.0f / N_NODES);
    float var  = m2 * (1.0f / N_NODES) - mean * mean;
    float inv  = 1.0f / sqrtf(var + BN_EPS);
    float sc   = g[j] * inv;
    scale[j] = sc;
    __shared__ float shl[64];
    shl[j] = b[j] - mean * sc;
    __syncthreads();
    float s = 0.f;
    for (int k = 0; k < DIM; k++) s += shl[k] * W[k * DIM + j];
    cshift[j] = s;
}

__global__ void k_bnfinal(const float* __restrict__ gsum, const float* __restrict__ gsumsq,
                          const float* __restrict__ g, const float* __restrict__ b,
                          float* __restrict__ scale, float* __restrict__ shift) {
    int j = threadIdx.x;
    float ms = 0.f, m2 = 0.f;
    for (int k = 0; k < NSLOT; k++) { ms += gsum[k * DIM + j]; m2 += gsumsq[k * DIM + j]; }
    float mean = ms * (1.0f / N_NODES);
    float var  = m2 * (1.0f / N_NODES) - mean * mean;
    float inv  = 1.0f / sqrtf(var + BN_EPS);
    float sc   = g[j] * inv;
    scale[j] = sc;
    shift[j] = b[j] - mean * sc;
}

// ---------------- GEMM (fp32 A): T(bf16) = (X*scale) @ W + cshift ----------------
__global__ __launch_bounds__(256) void k_gemm_f32(const float* __restrict__ X,
                                                  const float* __restrict__ W,
                                                  const float* __restrict__ scale,
                                                  const float* __restrict__ cshift,
                                                  unsigned short* __restrict__ T) {
    __shared__ float Wl[64 * 64];
    __shared__ float Al[64 * 65];
    for (int t = threadIdx.x; t < 4096; t += 256) {
        int k = t >> 6;
        Wl[t] = W[t] * scale[k];
    }
    int row0 = blockIdx.x * 64;
    for (int t = threadIdx.x; t < 4096; t += 256) {
        int r = t >> 6, k = t & 63;
        int i = row0 + r;
        Al[r * 65 + k] = (i < N_NODES) ? X[(size_t)i * DIM + k] : 0.f;
    }
    __syncthreads();
    int r = threadIdx.x & 63;
    int q = threadIdx.x >> 6;
    float acc[16];
    #pragma unroll
    for (int jj = 0; jj < 16; jj++) acc[jj] = cshift[q * 16 + jj];
    #pragma unroll 4
    for (int k = 0; k < 64; k++) {
        float a = Al[r * 65 + k];
        const float4* wv = (const float4*)&Wl[k * 64 + q * 16];
        float4 w0 = wv[0], w1 = wv[1], w2 = wv[2], w3 = wv[3];
        acc[0]  += a * w0.x; acc[1]  += a * w0.y; acc[2]  += a * w0.z; acc[3]  += a * w0.w;
        acc[4]  += a * w1.x; acc[5]  += a * w1.y; acc[6]  += a * w1.z; acc[7]  += a * w1.w;
        acc[8]  += a * w2.x; acc[9]  += a * w2.y; acc[10] += a * w2.z; acc[11] += a * w2.w;
        acc[12] += a * w3.x; acc[13] += a * w3.y; acc[14] += a * w3.z; acc[15] += a * w3.w;
    }
    int i = row0 + r;
    if (i < N_NODES) {
        unsigned int pk[8];
        #pragma unroll
        for (int jj = 0; jj < 8; jj++) pk[jj] = bf16_rtn2(acc[2 * jj], acc[2 * jj + 1]);
        uint4* outv = (uint4*)&T[(size_t)i * DIM + q * 16];
        outv[0] = make_uint4(pk[0], pk[1], pk[2], pk[3]);
        outv[1] = make_uint4(pk[4], pk[5], pk[6], pk[7]);
    }
}

// ---------------- GEMM (bf16 A): T(bf16) = (H*scale) @ W + cshift ----------------
__global__ __launch_bounds__(256) void k_gemm_b16(const unsigned short* __restrict__ X,
                                                  const float* __restrict__ W,
                                                  const float* __restrict__ scale,
                                                  const float* __restrict__ cshift,
                                                  unsigned short* __restrict__ T) {
    __shared__ float Wl[64 * 64];
    __shared__ float Al[64 * 65];
    for (int t = threadIdx.x; t < 4096; t += 256) {
        int k = t >> 6;
        Wl[t] = W[t] * scale[k];
    }
    int row0 = blockIdx.x * 64;
    for (int t = threadIdx.x; t < 4096; t += 256) {
        int r = t >> 6, k = t & 63;
        int i = row0 + r;
        Al[r * 65 + k] = (i < N_NODES) ? bfup(X[(size_t)i * DIM + k]) : 0.f;
    }
    __syncthreads();
    int r = threadIdx.x & 63;
    int q = threadIdx.x >> 6;
    float acc[16];
    #pragma unroll
    for (int jj = 0; jj < 16; jj++) acc[jj] = cshift[q * 16 + jj];
    #pragma unroll 4
    for (int k = 0; k < 64; k++) {
        float a = Al[r * 65 + k];
        const float4* wv = (const float4*)&Wl[k * 64 + q * 16];
        float4 w0 = wv[0], w1 = wv[1], w2 = wv[2], w3 = wv[3];
        acc[0]  += a * w0.x; acc[1]  += a * w0.y; acc[2]  += a * w0.z; acc[3]  += a * w0.w;
        acc[4]  += a * w1.x; acc[5]  += a * w1.y; acc[6]  += a * w1.z; acc[7]  += a * w1.w;
        acc[8]  += a * w2.x; acc[9]  += a * w2.y; acc[10] += a * w2.z; acc[11] += a * w2.w;
        acc[12] += a * w3.x; acc[13] += a * w3.y; acc[14] += a * w3.z; acc[15] += a * w3.w;
    }
    int i = row0 + r;
    if (i < N_NODES) {
        unsigned int pk[8];
        #pragma unroll
        for (int jj = 0; jj < 8; jj++) pk[jj] = bf16_rtn2(acc[2 * jj], acc[2 * jj + 1]);
        uint4* outv = (uint4*)&T[(size_t)i * DIM + q * 16];
        outv[0] = make_uint4(pk[0], pk[1], pk[2], pk[3]);
        outv[1] = make_uint4(pk[4], pk[5], pk[6], pk[7]);
    }
}

// ---------------- zero C rows of straddler nodes (idempotent) ----------------
__global__ __launch_bounds__(256) void k_zstrad(const int* __restrict__ rowstart,
                                                const int* __restrict__ winnode,
                                                float* __restrict__ C) {
    int lane = threadIdx.x & 63;
    int w = blockIdx.x * 4 + (threadIdx.x >> 6);
    int n = winnode[w];
    if (rowstart[n] < w * WIN)            // node continues into this window
        C[(size_t)n * DIM + lane] = 0.f;
}

// ---------------- gather layer 1: fused h = relu(agg+self+bias) -> H(bf16) + stats ------
// Window-complete nodes take the h-path; straddler segments atomicAdd into pre-zeroed C.
__global__ __launch_bounds__(256) void k_gather1(const unsigned short* __restrict__ T,
                                                 const float* __restrict__ dinv,
                                                 const int* __restrict__ rowstart,
                                                 const int* __restrict__ winnode,
                                                 const int2* __restrict__ csr_ew,
                                                 const float* __restrict__ bias,
                                                 float* __restrict__ C,
                                                 unsigned short* __restrict__ H,
                                                 float* __restrict__ gsum,
                                                 float* __restrict__ gsumsq) {
    int lane = threadIdx.x & 63;
    int w = blockIdx.x * 4 + (threadIdx.x >> 6);
    float bb = bias[lane];
    float s = 0.f, s2 = 0.f;
    int e = w * WIN;
    const int eend = e + WIN;
    int i  = __builtin_amdgcn_readfirstlane(winnode[w]);
    int re = __builtin_amdgcn_readfirstlane(rowstart[i + 1]);
    bool part = __builtin_amdgcn_readfirstlane(rowstart[i]) < e;
    float acc = 0.f;
    for (; e < eend; e += GU) {
        int src[GU]; float wt[GU];
        int eu = __builtin_amdgcn_readfirstlane(e);
        #pragma unroll
        for (int u = 0; u < GU; u++) {
            int2 ew = csr_ew[eu + u];
            src[u] = ew.x; wt[u] = __uint_as_float((unsigned int)ew.y);
        }
        float tv[GU];
        #pragma unroll
        for (int u = 0; u < GU; u++) tv[u] = bfup(T[(size_t)src[u] * DIM + lane]);
        #pragma unroll
        for (int u = 0; u < GU; u++) {
            while (e + u == re) {
                if (part) { atomicAdd(&C[(size_t)i * DIM + lane], acc); part = false; }
                else {
                    float di = dinv[i];
                    float h = fmaxf(acc + bfup(T[(size_t)i * DIM + lane]) * (di * di) + bb, 0.f);
                    H[(size_t)i * DIM + lane] = bf16r(h);
                    s += h; s2 += h * h;
                }
                acc = 0.f; ++i;
                re = __builtin_amdgcn_readfirstlane(rowstart[i + 1]);
            }
            acc += tv[u] * wt[u];
        }
    }
    if (part || re > eend) atomicAdd(&C[(size_t)i * DIM + lane], acc);
    else {
        float di = dinv[i];
        float h = fmaxf(acc + bfup(T[(size_t)i * DIM + lane]) * (di * di) + bb, 0.f);
        H[(size_t)i * DIM + lane] = bf16r(h);
        s += h; s2 += h * h;
    }
    __shared__ float ls[256], ls2[256];
    ls[threadIdx.x] = s; ls2[threadIdx.x] = s2;
    __syncthreads();
    if (threadIdx.x < 64) {
        int j = threadIdx.x;
        int slot = (blockIdx.x & (NSLOT - 1)) * DIM;
        atomicAdd(&gsum[slot + j],   ls[j] + ls[64 + j] + ls[128 + j] + ls[192 + j]);
        atomicAdd(&gsumsq[slot + j], ls2[j] + ls2[64 + j] + ls2[128 + j] + ls2[192 + j]);
    }
}

// ---------------- gather layer 2: fused h -> pool(run-flush) + stats (no H store) -------
__global__ __launch_bounds__(256) void k_gather2(const unsigned short* __restrict__ T,
                                                 const float* __restrict__ dinv,
                                                 const int* __restrict__ rowstart,
                                                 const int* __restrict__ winnode,
                                                 const int2* __restrict__ csr_ew,
                                                 const float* __restrict__ bias,
                                                 const int* __restrict__ batch,
                                                 float* __restrict__ C,
                                                 float* __restrict__ pool,
                                                 float* __restrict__ gsum,
                                                 float* __restrict__ gsumsq) {
    int lane = threadIdx.x & 63;
    int w = blockIdx.x * 4 + (threadIdx.x >> 6);
    float bb = bias[lane];
    float s = 0.f, s2 = 0.f, ps = 0.f;
    int cur_g = -1;
    int e = w * WIN;
    const int eend = e + WIN;
    int i  = __builtin_amdgcn_readfirstlane(winnode[w]);
    int re = __builtin_amdgcn_readfirstlane(rowstart[i + 1]);
    bool part = __builtin_amdgcn_readfirstlane(rowstart[i]) < e;
    float acc = 0.f;
    for (; e < eend; e += GU) {
        int src[GU]; float wt[GU];
        int eu = __builtin_amdgcn_readfirstlane(e);
        #pragma unroll
        for (int u = 0; u < GU; u++) {
            int2 ew = csr_ew[eu + u];
            src[u] = ew.x; wt[u] = __uint_as_float((unsigned int)ew.y);
        }
        float tv[GU];
        #pragma unroll
        for (int u = 0; u < GU; u++) tv[u] = bfup(T[(size_t)src[u] * DIM + lane]);
        #pragma unroll
        for (int u = 0; u < GU; u++) {
            while (e + u == re) {
                if (part) { atomicAdd(&C[(size_t)i * DIM + lane], acc); part = false; }
                else {
                    float di = dinv[i];
                    float h = fmaxf(acc + bfup(T[(size_t)i * DIM + lane]) * (di * di) + bb, 0.f);
                    s += h; s2 += h * h;
                    int g = batch[i];
                    if (g != cur_g) {
                        if (cur_g >= 0) atomicAdd(&pool[(size_t)cur_g * DIM + lane], ps);
                        ps = 0.f; cur_g = g;
                    }
                    ps += h;
                }
                acc = 0.f; ++i;
                re = __builtin_amdgcn_readfirstlane(rowstart[i + 1]);
            }
            acc += tv[u] * wt[u];
        }
    }
    if (part || re > eend) atomicAdd(&C[(size_t)i * DIM + lane], acc);
    else {
        float di = dinv[i];
        float h = fmaxf(acc + bfup(T[(size_t)i * DIM + lane]) * (di * di) + bb, 0.f);
        s += h; s2 += h * h;
        int g = batch[i];
        if (g != cur_g) {
            if (cur_g >= 0) atomicAdd(&pool[(size_t)cur_g * DIM + lane], ps);
            ps = 0.f; cur_g = g;
        }
        ps += h;
    }
    if (cur_g >= 0) atomicAdd(&pool[(size_t)cur_g * DIM + lane], ps);
    __shared__ float ls[256], ls2[256];
    ls[threadIdx.x] = s; ls2[threadIdx.x] = s2;
    __syncthreads();
    if (threadIdx.x < 64) {
        int j = threadIdx.x;
        int slot = (blockIdx.x & (NSLOT - 1)) * DIM;
        atomicAdd(&gsum[slot + j],   ls[j] + ls[64 + j] + ls[128 + j] + ls[192 + j]);
        atomicAdd(&gsumsq[slot + j], ls2[j] + ls2[64 + j] + ls2[128 + j] + ls2[192 + j]);
    }
}

// ---------------- straddler + boundary-deg0 finish, layer 1 (-> H + stats) --------------
// blocks [0, NWIN/4): windows role — unique owner window (w == rs/WIN + 1) finishes node
// blocks [NWIN/4, +392): deg0 role — nodes with deg==0 and rowstart%WIN==0 (missed by gather)
__global__ __launch_bounds__(256) void k_strad1(const float* __restrict__ C,
                                                const unsigned short* __restrict__ T,
                                                const float* __restrict__ dinv,
                                                const int* __restrict__ rowstart,
                                                const int* __restrict__ winnode,
                                                const float* __restrict__ bias,
                                                unsigned short* __restrict__ H,
                                                float* __restrict__ gsum,
                                                float* __restrict__ gsumsq) {
    int lane = threadIdx.x & 63;
    int wv = threadIdx.x >> 6;
    float bb = bias[lane];
    float s = 0.f, s2 = 0.f;
    __shared__ int anyw;
    if (threadIdx.x == 0) anyw = 0;
    __syncthreads();
    if (blockIdx.x < NWIN / 4) {
        int w = blockIdx.x * 4 + wv;
        int n = winnode[w];
        int rs = rowstart[n];
        if (w == rs / WIN + 1) {
            float di = dinv[n];
            float h = fmaxf(C[(size_t)n * DIM + lane]
                            + bfup(T[(size_t)n * DIM + lane]) * (di * di) + bb, 0.f);
            H[(size_t)n * DIM + lane] = bf16r(h);
            s += h; s2 += h * h;
            anyw = 1;
        }
    } else {
        int base = (blockIdx.x - NWIN / 4) * 256 + wv * 64;
        int nb = base + lane;
        int d0 = 0;
        if (nb < N_NODES)
            d0 = (rowstart[nb + 1] == rowstart[nb]) && ((rowstart[nb] & (WIN - 1)) == 0);
        unsigned long long m = __ballot(d0);
        while (m) {
            int b = __builtin_ctzll(m);
            m &= m - 1;
            int n = base + b;
            float di = dinv[n];
            float h = fmaxf(bfup(T[(size_t)n * DIM + lane]) * (di * di) + bb, 0.f);
            H[(size_t)n * DIM + lane] = bf16r(h);
            s += h; s2 += h * h;
            anyw = 1;
        }
    }
    __shared__ float ls[256], ls2[256];
    ls[threadIdx.x] = s; ls2[threadIdx.x] = s2;
    __syncthreads();
    if (anyw && threadIdx.x < 64) {
        int j = threadIdx.x;
        int slot = (blockIdx.x & (NSLOT - 1)) * DIM;
        atomicAdd(&gsum[slot + j],   ls[j] + ls[64 + j] + ls[128 + j] + ls[192 + j]);
        atomicAdd(&gsumsq[slot + j], ls2[j] + ls2[64 + j] + ls2[128 + j] + ls2[192 + j]);
    }
}

// ---------------- straddler + boundary-deg0 finish, layer 2 (-> pool + stats) -----------
__global__ __launch_bounds__(256) void k_strad2(const float* __restrict__ C,
                                                const unsigned short* __restrict__ T,
                                                const float* __restrict__ dinv,
                                                const int* __restrict__ rowstart,
                                                const int* __restrict__ winnode,
                                                const float* __restrict__ bias,
                                                const int* __restrict__ batch,
                                                float* __restrict__ pool,
                                                float* __restrict__ gsum,
                                                float* __restrict__ gsumsq) {
    int lane = threadIdx.x & 63;
    int wv = threadIdx.x >> 6;
    float bb = bias[lane];
    float s = 0.f, s2 = 0.f;
    __shared__ int anyw;
    if (threadIdx.x == 0) anyw = 0;
    __syncthreads();
    if (blockIdx.x < NWIN / 4) {
        int w = blockIdx.x * 4 + wv;
        int n = winnode[w];
        int rs = rowstart[n];
        if (w == rs / WIN + 1) {
            float di = dinv[n];
            float h = fmaxf(C[(size_t)n * DIM + lane]
                            + bfup(T[(size_t)n * DIM + lane]) * (di * di) + bb, 0.f);
            s += h; s2 += h * h;
            atomicAdd(&pool[(size_t)batch[n] * DIM + lane], h);
            anyw = 1;
        }
    } else {
        int base = (blockIdx.x - NWIN / 4) * 256 + wv * 64;
        int nb = base + lane;
        int d0 = 0;
        if (nb < N_NODES)
            d0 = (rowstart[nb + 1] == rowstart[nb]) && ((rowstart[nb] & (WIN - 1)) == 0);
        unsigned long long m = __ballot(d0);
        while (m) {
            int b = __builtin_ctzll(m);
            m &= m - 1;
            int n = base + b;
            float di = dinv[n];
            float h = fmaxf(bfup(T[(size_t)n * DIM + lane]) * (di * di) + bb, 0.f);
            s += h; s2 += h * h;
            atomicAdd(&pool[(size_t)batch[n] * DIM + lane], h);
            anyw = 1;
        }
    }
    __shared__ float ls[256], ls2[256];
    ls[threadIdx.x] = s; ls2[threadIdx.x] = s2;
    __syncthreads();
    if (anyw && threadIdx.x < 64) {
        int j = threadIdx.x;
        int slot = (blockIdx.x & (NSLOT - 1)) * DIM;
        atomicAdd(&gsum[slot + j],   ls[j] + ls[64 + j] + ls[128 + j] + ls[192 + j]);
        atomicAdd(&gsumsq[slot + j], ls2[j] + ls2[64 + j] + ls2[128 + j] + ls2[192 + j]);
    }
}

// ---------------- final: out[g] = ((pool/cnt)*scale + shift) @ Wout + bout ----------------
__global__ void k_final(const float* __restrict__ pool, const int* __restrict__ start,
                        const float* __restrict__ scale, const float* __restrict__ shift,
                        const float* __restrict__ Wout, const float* __restrict__ bout,
                        float* __restrict__ out) {
    int g = blockIdx.x;
    int l = threadIdx.x;
    float c = fmaxf((float)(start[g + 1] - start[g]), 1.f);
    float p = (pool[g * DIM + l] / c) * scale[l] + shift[l];
    float a0 = p * Wout[l * 2 + 0];
    float a1 = p * Wout[l * 2 + 1];
    #pragma unroll
    for (int off = 32; off; off >>= 1) {
        a0 += __shfl_down(a0, off, 64);
        a1 += __shfl_down(a1, off, 64);
    }
    if (l == 0) {
        out[g * 2 + 0] = a0 + bout[0];
        out[g * 2 + 1] = a1 + bout[1];
    }
}

extern "C" void kernel_launch(void* const* d_in, const int* in_sizes, int n_in,
                              void* d_out, int out_size, void* d_ws, size_t ws_size,
                              hipStream_t stream) {
    (void)in_sizes; (void)n_in; (void)out_size; (void)ws_size;
    const float* x       = (const float*)d_in[0];
    const int*   ei      = (const int*)d_in[1];
    const int*   batch   = (const int*)d_in[2];
    const float* bn_in_g = (const float*)d_in[3];
    const float* bn_in_b = (const float*)d_in[4];
    const float* W1      = (const float*)d_in[5];
    const float* b1      = (const float*)d_in[6];
    const float* g1      = (const float*)d_in[7];
    const float* be1     = (const float*)d_in[8];
    const float* W2      = (const float*)d_in[9];
    const float* b2      = (const float*)d_in[10];
    const float* g2      = (const float*)d_in[11];
    const float* be2     = (const float*)d_in[12];
    const float* Wout    = (const float*)d_in[13];
    const float* bout    = (const float*)d_in[14];
    float* out = (float*)d_out;

    // workspace layout (~64 MB), 8B alignment for int2
    char* p = (char*)d_ws;
    float* C = (float*)p;                   p += (size_t)N_NODES * DIM * 4;  // 25.6 MB
    unsigned short* H = (unsigned short*)p; p += (size_t)N_NODES * DIM * 2;  // 12.8 MB (bf16)
    unsigned short* T = (unsigned short*)p; p += (size_t)N_NODES * DIM * 2;  // 12.8 MB
    int2* csr_ew = (int2*)p;                p += (size_t)N_EDGES * 8;        // 10.24 MB
    float* dinv = (float*)p;                p += N_NODES * 4;
    int* bh = (int*)p;                      p += NB * P1B * 4;
    int* iscan = (int*)p;                   p += NB * P1B * 4;
    int* rowstart = (int*)p;                p += (N_NODES + 2) * 4;
    int* winnode = (int*)p;                 p += NWIN * 4;
    int* bsum = (int*)p;                    p += NB * 4;
    int* boff = (int*)p;                    p += NB * 4;
    int* start = (int*)p;                   p += (N_GRAPHS + 2) * 4;
    float* gsum = (float*)p;                p += NSLOT * DIM * 4;  // gsum|gsumsq contiguous
    float* gsumsq = (float*)p;              p += NSLOT * DIM * 4;
    float* scale = (float*)p;               p += DIM * 4;
    float* shift = (float*)p;               p += DIM * 4;
    float* cshift = (float*)p;              p += DIM * 4;
    float* pool = (float*)p;                p += (size_t)N_GRAPHS * DIM * 4;
    int2* tmp = (int2*)H;  // bucket-sort temp aliases H (dead before k_gather1 writes H)

    // ---- CSR build (LDS bucket sort) + BN-input stats + graph boundaries ----
    hipMemsetAsync(gsum, 0, 2 * NSLOT * DIM * sizeof(float), stream);
    hipMemsetAsync(pool, 0, (size_t)N_GRAPHS * DIM * sizeof(float), stream);
    k_p1hist<<<P1B + SB + 392, 256, 0, stream>>>(ei, batch, x, bh, start, gsum, gsumsq);
    k_scan1<<<NB, 256, 0, stream>>>(bh, iscan, bsum);
    k_scan2<<<1, 512, 0, stream>>>(bsum, boff);
    k_p1scat<<<P1B, 256, 0, stream>>>(ei, bh, iscan, boff, tmp);
    k_p2a<<<NB, 256, 0, stream>>>(tmp, bh, iscan, boff, rowstart, dinv, winnode);
    k_p2b<<<NB, 256, 0, stream>>>(tmp, bh, iscan, boff, rowstart, dinv, csr_ew);

    // ---- input BN -> GEMM1 -> gather1 (fused relu+H(bf16)+stats) -> straddle finish ----
    k_bnfold<<<1, 64, 0, stream>>>(gsum, gsumsq, bn_in_g, bn_in_b, W1, scale, cshift);
    k_gemm_f32<<<(N_NODES + 63) / 64, 256, 0, stream>>>(x, W1, scale, cshift, T);
    k_zstrad<<<NWIN / 4, 256, 0, stream>>>(rowstart, winnode, C);
    k_gather1<<<NWIN / 4, 256, 0, stream>>>(T, dinv, rowstart, winnode, csr_ew, b1,
                                            C, H, gsum, gsumsq);
    k_strad1<<<NWIN / 4 + 392, 256, 0, stream>>>(C, T, dinv, rowstart, winnode, b1,
                                                 H, gsum, gsumsq);

    // ---- BN1 -> GEMM2 (bf16 A) -> gather2 (fused relu+pool+stats) -> straddle finish ----
    k_bnfold<<<1, 64, 0, stream>>>(gsum, gsumsq, g1, be1, W2, scale, cshift);
    k_gemm_b16<<<(N_NODES + 63) / 64, 256, 0, stream>>>(H, W2, scale, cshift, T);
    k_zstrad<<<NWIN / 4, 256, 0, stream>>>(rowstart, winnode, C);
    k_gather2<<<NWIN / 4, 256, 0, stream>>>(T, dinv, rowstart, winnode, csr_ew, b2,
                                            batch, C, pool, gsum, gsumsq);
    k_strad2<<<NWIN / 4 + 392, 256, 0, stream>>>(C, T, dinv, rowstart, winnode, b2,
                                                 batch, pool, gsum, gsumsq);

    // ---- BN2 (post-pool; BN affine, pool linear) -> linear ----
    k_bnfinal<<<1, 64, 0, stream>>>(gsum, gsumsq, g2, be2, scale, shift);
    k_final<<<N_GRAPHS, 64, 0, stream>>>(pool, start, scale, shift, Wout, bout, out);
}